// Round 1
// baseline (1509.564 us; speedup 1.0000x reference)
//
#include <hip/hip_runtime.h>
#include <hip/hip_bf16.h>

using bf16 = __hip_bfloat16;

constexpr int kDim = 192;
constexpr int kH = 6;
constexpr int kHd = 32;
constexpr int kN = 64;
constexpr int kT = 64;
constexpr int kV = 25;
constexpr int kP = kT * kV;            // 1600 positions per n
constexpr int kNCstride = kDim * kP;   // 307200, per-n stride of (c,t,v)
constexpr float kScale = 0.17677669529663687f;  // 32^-0.5
constexpr float kCoeff = 0.4f;

// ---------------- h_adj (25x25) from joint labels ----------------
__global__ void hadj_kernel(const int* __restrict__ jl,
                            const float* __restrict__ hew,
                            float* __restrict__ hadj) {
  __shared__ int lbl[kV];
  __shared__ int cnt[8];
  int t = threadIdx.x;
  if (t < 8) cnt[t] = 0;
  __syncthreads();
  if (t < kV) { lbl[t] = jl[t]; atomicAdd(&cnt[lbl[t]], 1); }
  __syncthreads();
  for (int idx = t; idx < kV * kV; idx += 64) {
    int v = idx / kV, w = idx - v * kV;
    float val = 0.f;
    if (lbl[v] == lbl[w]) val = hew[lbl[v]] / (float)cnt[lbl[v]];
    hadj[idx] = val;
  }
}

// ---- GEMM: out[n,o,p](bf16) = sum_c W[o,c] * X[n,c,p], optional LN on X ----
// Tile 64(o) x 128(p), BK=16, 256 threads, 8x4 micro-tile per thread.
template <int LN>
__global__ void __launch_bounds__(256) gemm_kernel(
    const float* __restrict__ X, const float* __restrict__ W0,
    const float* __restrict__ W1, bf16* __restrict__ out, int M,
    const float* __restrict__ mu, const float* __restrict__ rstd,
    const float* __restrict__ lng, const float* __restrict__ lnb) {
  __shared__ float Wt[16][68];    // [k][o], padded stride 68 (16B-aligned rows)
  __shared__ float Xt[16][128];   // [k][p]
  const int tid = threadIdx.x;
  const int n = blockIdx.z;
  const int ob = blockIdx.y * 64;
  const int pb = blockIdx.x * 128;
  const float* Xn = X + (size_t)n * kNCstride;
  float acc[8][4];
#pragma unroll
  for (int i = 0; i < 8; ++i)
#pragma unroll
    for (int j = 0; j < 4; ++j) acc[i][j] = 0.f;
  const int to8 = tid >> 5;       // 0..7 : o octet
  const int tp2 = tid & 31;       // 0..31: p quad
  const int so = tid >> 2;        // 0..63: o for W staging
  const int skq = tid & 3;        // 0..3 : k quad for W staging
  const int sk = tid >> 4;        // 0..15: k for X staging
  const int sp = (tid & 15) * 8;  // p octet base for X staging
  const int og = ob + so;
  const float* Wr = (og < kDim) ? (W0 + (size_t)og * kDim)
                                : (W1 + (size_t)(og - kDim) * kDim);
  for (int kb = 0; kb < kDim; kb += 16) {
    // stage W tile (transposed to [k][o])
    float4 wv = *reinterpret_cast<const float4*>(Wr + kb + skq * 4);
    Wt[skq * 4 + 0][so] = wv.x;
    Wt[skq * 4 + 1][so] = wv.y;
    Wt[skq * 4 + 2][so] = wv.z;
    Wt[skq * 4 + 3][so] = wv.w;
    // stage X tile (optionally LayerNorm'd)
    int c = kb + sk;
    float gc = 0.f, bc = 0.f;
    if (LN) { gc = lng[c]; bc = lnb[c]; }
    const float* Xr = Xn + (size_t)c * kP;
#pragma unroll
    for (int j = 0; j < 8; ++j) {
      int p = pb + sp + j;
      float xv = 0.f;
      if (p < kP) {
        xv = Xr[p];
        if (LN) {
          int mi = n * kP + p;
          xv = (xv - mu[mi]) * rstd[mi] * gc + bc;
        }
      }
      Xt[sk][sp + j] = xv;
    }
    __syncthreads();
#pragma unroll
    for (int kk = 0; kk < 16; ++kk) {
      float4 xv = *reinterpret_cast<const float4*>(&Xt[kk][tp2 * 4]);
      float4 wA = *reinterpret_cast<const float4*>(&Wt[kk][to8 * 8]);
      float4 wB = *reinterpret_cast<const float4*>(&Wt[kk][to8 * 8 + 4]);
      float xs[4] = {xv.x, xv.y, xv.z, xv.w};
      float wsv[8] = {wA.x, wA.y, wA.z, wA.w, wB.x, wB.y, wB.z, wB.w};
#pragma unroll
      for (int i = 0; i < 8; ++i)
#pragma unroll
        for (int j = 0; j < 4; ++j) acc[i][j] += wsv[i] * xs[j];
    }
    __syncthreads();
  }
#pragma unroll
  for (int i = 0; i < 8; ++i) {
    int o = ob + to8 * 8 + i;
    size_t base = ((size_t)n * M + o) * kP;
#pragma unroll
    for (int j = 0; j < 4; ++j) {
      int p = pb + tp2 * 4 + j;
      if (p < kP) out[base + p] = __float2bfloat16(acc[i][j]);
    }
  }
}

// ------- in-place row transform: OP[row,:] = OP[row,:] @ h_adj (25x25) -------
__global__ void __launch_bounds__(256) hadj_apply_kernel(
    bf16* __restrict__ OP, const float* __restrict__ hadj) {
  __shared__ float ha[kV * kV];
  const int tid = threadIdx.x;
  for (int i = tid; i < kV * kV; i += 256) ha[i] = hadj[i];
  __syncthreads();
  size_t row = (size_t)blockIdx.x * 256 + tid;  // rows = N*DIM*T = 786432 exact
  size_t base = row * kV;
  float xr[kV];
#pragma unroll
  for (int v = 0; v < kV; ++v) xr[v] = __bfloat162float(OP[base + v]);
#pragma unroll
  for (int w = 0; w < kV; ++w) {
    float a = 0.f;
#pragma unroll
    for (int v = 0; v < kV; ++v) a += xr[v] * ha[v * kV + w];
    OP[base + w] = __float2bfloat16(a);
  }
}

// ---------------- per-(n,t,v) LayerNorm statistics over c ----------------
__global__ void musd_kernel(const float* __restrict__ x, float* __restrict__ mu,
                            float* __restrict__ rstd) {
  int id = blockIdx.x * 256 + threadIdx.x;  // exactly N*P = 102400
  int n = id / kP, p = id - n * kP;
  const float* px = x + (size_t)n * kNCstride + p;
  float s = 0.f, s2 = 0.f;
  for (int c = 0; c < kDim; ++c) {
    float v = px[(size_t)c * kP];
    s += v;
    s2 += v * v;
  }
  float m = s * (1.f / kDim);
  float var = s2 * (1.f / kDim) - m * m;
  mu[id] = m;
  rstd[id] = rsqrtf(var + 1e-5f);
}

// ---------------- s[n,t] = mean over (c,v) of OP ----------------
__global__ void sred_kernel(const bf16* __restrict__ OP, float* __restrict__ s) {
  int nt = blockIdx.x;
  int n = nt / kT, t = nt - n * kT;
  int lane = threadIdx.x;
  size_t base = (size_t)n * kNCstride + t * kV;
  float sum = 0.f;
  for (int j = lane; j < kDim * kV; j += 64) {
    int c = j / kV, v = j - c * kV;
    sum += __bfloat162float(OP[base + (size_t)c * kP + v]);
  }
  for (int off = 32; off > 0; off >>= 1) sum += __shfl_down(sum, off);
  if (lane == 0) s[nt] = sum * (1.f / (kDim * kV));
}

// ---------------- SE gate MLP -> factor f[n,t] = 1 + 0.4*sigmoid(...) -------
__global__ void gate_kernel(const float* __restrict__ s,
                            const float* __restrict__ w1l,
                            const float* __restrict__ b1,
                            const float* __restrict__ w2l,
                            const float* __restrict__ b2,
                            float* __restrict__ gatef) {
  __shared__ float sh[kT];
  __shared__ float hid[12];
  int n = blockIdx.x, t = threadIdx.x;
  sh[t] = s[n * kT + t];
  __syncthreads();
  if (t < 12) {
    float a = b1[t];
    for (int j = 0; j < kT; ++j) a += sh[j] * w1l[t * kT + j];
    hid[t] = fmaxf(a, 0.f);
  }
  __syncthreads();
  float a = b2[t];
  for (int j = 0; j < 12; ++j) a += hid[j] * w2l[t * 12 + j];
  float g = 1.f / (1.f + __expf(-a));
  gatef[n * kT + t] = 1.f + kCoeff * g;
}

// ------- attention per (n,t,h): scores, softmax, PV, grouped proj, residual -
__global__ void __launch_bounds__(256) attn_kernel(
    const bf16* __restrict__ QKV, const bf16* __restrict__ OP,
    const float* __restrict__ gatef, const int* __restrict__ hops,
    const float* __restrict__ rpe, int n_hop, const float* __restrict__ w1,
    const float* __restrict__ outer, const float* __restrict__ alpha_p,
    const float* __restrict__ proj_w, const float* __restrict__ proj_b,
    const float* __restrict__ x, float* __restrict__ out) {
  __shared__ float qs[kV * 33], ks[kV * 33], es[kV * 33], vs[kV * 33],
      os[kV * 33];
  __shared__ float rpe_s[kV * 33];
  __shared__ float sc[kV * 26];
  __shared__ float outer_s[kV * kV];
  __shared__ int hops_s[kV * kV];
  __shared__ float dterm[kV];
  __shared__ float pw[kHd * 33];
  const int tid = threadIdx.x;
  const int b = blockIdx.x;
  const int h = b % kH;
  const int nt = b / kH;
  const int t = nt % kT;
  const int n = nt / kT;
  const float f = gatef[nt];
  const float alpha = alpha_p[0];
  const size_t qbase =
      (size_t)n * (3 * kDim * kP) + (size_t)(h * kHd) * kP + t * kV;
  const size_t ebase = (size_t)n * kNCstride + (size_t)(h * kHd) * kP + t * kV;
  for (int idx = tid; idx < kV * kHd; idx += 256) {
    int d = idx / kV, v = idx - d * kV;
    qs[v * 33 + d] = __bfloat162float(QKV[qbase + (size_t)d * kP + v]);
    ks[v * 33 + d] = __bfloat162float(QKV[qbase + (size_t)(kDim + d) * kP + v]);
    vs[v * 33 + d] =
        __bfloat162float(QKV[qbase + (size_t)(2 * kDim + d) * kP + v]);
    es[v * 33 + d] = __bfloat162float(OP[ebase + (size_t)d * kP + v]) * f;
  }
  for (int idx = tid; idx < n_hop * kHd; idx += 256) {
    int hp = idx >> 5, d = idx & 31;
    rpe_s[hp * 33 + d] = rpe[hp * kDim + h * kHd + d];
  }
  for (int idx = tid; idx < kV * kV; idx += 256) {
    hops_s[idx] = hops[idx];
    outer_s[idx] = outer[h * kV * kV + idx];
  }
  for (int idx = tid; idx < kHd * kHd; idx += 256) {
    int oo = idx >> 5, i = idx & 31;
    pw[oo * 33 + i] = proj_w[(h * kHd + oo) * kHd + i];
  }
  __syncthreads();
  if (tid < kV) {
    float a = 0.f;
#pragma unroll
    for (int d = 0; d < kHd; ++d) a += w1[h * kHd + d] * es[tid * 33 + d];
    dterm[tid] = a;
  }
  __syncthreads();
  // scores: (q . (k + e + rpe[hop])) + dterm, scaled
  for (int idx = tid; idx < kV * kV; idx += 256) {
    int v = idx / kV, ww = idx - v * kV;
    int hp = hops_s[idx];
    float a = dterm[ww];
    const float* qv = &qs[v * 33];
    const float* kw = &ks[ww * 33];
    const float* ew = &es[ww * 33];
    const float* rp = &rpe_s[hp * 33];
#pragma unroll
    for (int d = 0; d < kHd; ++d) a += qv[d] * (kw[d] + ew[d] + rp[d]);
    sc[v * 26 + ww] = a * kScale;
  }
  __syncthreads();
  // softmax rows, then p = alpha*attn + outer
  if (tid < kV) {
    float m = -1e30f;
    for (int ww = 0; ww < kV; ++ww) m = fmaxf(m, sc[tid * 26 + ww]);
    float ssum = 0.f;
    for (int ww = 0; ww < kV; ++ww) {
      float e = __expf(sc[tid * 26 + ww] - m);
      sc[tid * 26 + ww] = e;
      ssum += e;
    }
    float inv = alpha / ssum;
    for (int ww = 0; ww < kV; ++ww)
      sc[tid * 26 + ww] = sc[tid * 26 + ww] * inv + outer_s[tid * kV + ww];
  }
  __syncthreads();
  // o = p @ v
  for (int idx = tid; idx < kV * kHd; idx += 256) {
    int v = idx >> 5, d = idx & 31;
    float a = 0.f;
#pragma unroll
    for (int ww = 0; ww < kV; ++ww) a += sc[v * 26 + ww] * vs[ww * 33 + d];
    os[v * 33 + d] = a;
  }
  __syncthreads();
  // grouped 32x32 projection + bias + residual, write final output
  for (int idx = tid; idx < kV * kHd; idx += 256) {
    int oo = idx / kV, v = idx - oo * kV;
    float a = proj_b[h * kHd + oo];
#pragma unroll
    for (int i = 0; i < kHd; ++i) a += pw[oo * 33 + i] * os[v * 33 + i];
    size_t oaddr =
        (size_t)n * kNCstride + (size_t)(h * kHd + oo) * kP + t * kV + v;
    out[oaddr] = x[oaddr] + a;
  }
}

extern "C" void kernel_launch(void* const* d_in, const int* in_sizes, int n_in,
                              void* d_out, int out_size, void* d_ws,
                              size_t ws_size, hipStream_t stream) {
  const float* x = (const float*)d_in[0];
  const int* joint_label = (const int*)d_in[1];
  const float* he_weight = (const float*)d_in[3];
  const int* hops = (const int*)d_in[4];
  const float* ln_g = (const float*)d_in[5];
  const float* ln_b = (const float*)d_in[6];
  const float* hgc_w = (const float*)d_in[7];
  const float* q_w = (const float*)d_in[8];
  const float* kv_w = (const float*)d_in[9];
  const float* proj_w = (const float*)d_in[10];
  const float* proj_b = (const float*)d_in[11];
  const float* rpe = (const float*)d_in[12];
  const float* w1 = (const float*)d_in[13];
  const float* outer = (const float*)d_in[14];
  const float* alpha = (const float*)d_in[15];
  const float* lin1_w = (const float*)d_in[16];
  const float* lin1_b = (const float*)d_in[17];
  const float* lin2_w = (const float*)d_in[18];
  const float* lin2_b = (const float*)d_in[19];
  const int n_hop = in_sizes[12] / kDim;

  char* w = (char*)d_ws;
  bf16* OP = (bf16*)w;
  w += (size_t)kN * kDim * kP * 2;        // 39.3 MB
  bf16* QKV = (bf16*)w;
  w += (size_t)kN * 3 * kDim * kP * 2;    // 118 MB (rows: 0..191 Q, K, V)
  float* hadj = (float*)w;
  w += 640 * 4;
  float* s_ws = (float*)w;
  w += kN * kT * 4;
  float* gatef = (float*)w;
  w += kN * kT * 4;
  float* mu = (float*)w;
  w += kN * kP * 4;
  float* rstd = (float*)w;
  w += kN * kP * 4;

  hipLaunchKernelGGL(hadj_kernel, dim3(1), dim3(64), 0, stream, joint_label,
                     he_weight, hadj);
  // OP = hgc_w @ x  (no LN)
  hipLaunchKernelGGL((gemm_kernel<0>), dim3(13, 3, kN), dim3(256), 0, stream, x,
                     hgc_w, hgc_w, OP, kDim, nullptr, nullptr, nullptr,
                     nullptr);
  // OP rows <- OP rows @ h_adj (commutes with channel GEMM)
  hipLaunchKernelGGL(hadj_apply_kernel, dim3(3072), dim3(256), 0, stream, OP,
                     hadj);
  hipLaunchKernelGGL(sred_kernel, dim3(kN * kT), dim3(64), 0, stream, OP, s_ws);
  hipLaunchKernelGGL(gate_kernel, dim3(kN), dim3(kT), 0, stream, s_ws, lin1_w,
                     lin1_b, lin2_w, lin2_b, gatef);
  hipLaunchKernelGGL(musd_kernel, dim3(400), dim3(256), 0, stream, x, mu, rstd);
  // QKV = [q_w; kv_w] @ LN(x)
  hipLaunchKernelGGL((gemm_kernel<1>), dim3(13, 9, kN), dim3(256), 0, stream, x,
                     q_w, kv_w, QKV, 3 * kDim, mu, rstd, ln_g, ln_b);
  hipLaunchKernelGGL(attn_kernel, dim3(kN * kT * kH), dim3(256), 0, stream, QKV,
                     OP, gatef, hops, rpe, n_hop, w1, outer, alpha, proj_w,
                     proj_b, x, (float*)d_out);
}

// Round 2
// 622.934 us; speedup vs baseline: 2.4233x; 2.4233x over previous
//
#include <hip/hip_runtime.h>
#include <hip/hip_bf16.h>

using bf16 = __hip_bfloat16;
typedef __bf16 bf16x8 __attribute__((ext_vector_type(8)));
typedef float f32x4 __attribute__((ext_vector_type(4)));

constexpr int kDim = 192;
constexpr int kH = 6;
constexpr int kHd = 32;
constexpr int kN = 64;
constexpr int kT = 64;
constexpr int kV = 25;
constexpr int kP = kT * kV;            // 1600 positions per n
constexpr int kNCstride = kDim * kP;   // 307200, per-n stride of (c,t,v)
constexpr float kScale = 0.17677669529663687f;  // 32^-0.5
constexpr float kCoeff = 0.4f;

// ---------------- h_adj (25x25) from joint labels ----------------
__global__ void hadj_kernel(const int* __restrict__ jl,
                            const float* __restrict__ hew,
                            float* __restrict__ hadj) {
  __shared__ int lbl[kV];
  __shared__ int cnt[8];
  int t = threadIdx.x;
  if (t < 8) cnt[t] = 0;
  __syncthreads();
  if (t < kV) { lbl[t] = jl[t]; atomicAdd(&cnt[lbl[t]], 1); }
  __syncthreads();
  for (int idx = t; idx < kV * kV; idx += 64) {
    int v = idx / kV, w = idx - v * kV;
    float val = 0.f;
    if (lbl[v] == lbl[w]) val = hew[lbl[v]] / (float)cnt[lbl[v]];
    hadj[idx] = val;
  }
}

// ---------------- weights fp32 -> bf16, combined [hgc;q;kv] 768x192 ---------
__global__ void wconv_kernel(const float* __restrict__ hgc,
                             const float* __restrict__ qw,
                             const float* __restrict__ kvw,
                             bf16* __restrict__ Wb) {
  int i = blockIdx.x * 256 + threadIdx.x;  // 768*192 = 147456 exact
  float v;
  if (i < 36864) v = hgc[i];
  else if (i < 73728) v = qw[i - 36864];
  else v = kvw[i - 73728];
  Wb[i] = __float2bfloat16(v);
}

// ------- prep per (n,t): stage x slab, LN stats, h_adj apply, emit bf16 -----
// XB[n][p][c] = bf16( sum_v x[n][c][t,v] * hadj[v][w] )   (z, k-contiguous)
// XL[n][p][c] = bf16( LN(x)[n][c][t,v] )                  (k-contiguous)
__global__ void __launch_bounds__(256) prep_kernel(
    const float* __restrict__ x, const float* __restrict__ hadjg,
    const float* __restrict__ lng, const float* __restrict__ lnb,
    bf16* __restrict__ XB, bf16* __restrict__ XL) {
  __shared__ float xs[kV][193];
  __shared__ float ha[kV * kV];
  __shared__ float ps[kV][8], ps2[kV][8];
  __shared__ float mus[kV], rsd[kV];
  const int tid = threadIdx.x;
  const int t = blockIdx.x, n = blockIdx.y;
  for (int i = tid; i < kV * kV; i += 256) ha[i] = hadjg[i];
  const float* xb = x + (size_t)n * kNCstride + t * kV;
  for (int idx = tid; idx < kDim * kV; idx += 256) {
    int c = idx / kV, p = idx - c * kV;
    xs[p][c] = xb[(size_t)c * kP + p];
  }
  __syncthreads();
  if (tid < 200) {
    int p = tid >> 3, q = tid & 7;
    float a = 0.f, b = 0.f;
    int c0 = q * 24;
    for (int c = c0; c < c0 + 24; ++c) { float v = xs[p][c]; a += v; b += v * v; }
    ps[p][q] = a; ps2[p][q] = b;
  }
  __syncthreads();
  if (tid < kV) {
    float a = 0.f, b = 0.f;
    for (int q = 0; q < 8; ++q) { a += ps[tid][q]; b += ps2[tid][q]; }
    float m = a * (1.f / kDim);
    float var = b * (1.f / kDim) - m * m;
    mus[tid] = m; rsd[tid] = rsqrtf(var + 1e-5f);
  }
  __syncthreads();
  size_t obase = ((size_t)n * kP + t * kV) * kDim;
  for (int idx = tid; idx < 600; idx += 256) {
    int p = idx / 24, cc = (idx - p * 24) * 8;
    float m = mus[p], r = rsd[p];
    union { uint2 u[2]; bf16 b[8]; } pk;
#pragma unroll
    for (int i = 0; i < 8; ++i) {
      int c = cc + i;
      pk.b[i] = __float2bfloat16((xs[p][c] - m) * r * lng[c] + lnb[c]);
    }
    *reinterpret_cast<uint2*>(XL + obase + p * kDim + cc) = pk.u[0];
    *reinterpret_cast<uint2*>(XL + obase + p * kDim + cc + 4) = pk.u[1];
  }
  for (int idx = tid; idx < 600; idx += 256) {
    int w = idx / 24, cc = (idx - w * 24) * 8;
    float acc[8] = {0.f, 0.f, 0.f, 0.f, 0.f, 0.f, 0.f, 0.f};
    for (int v = 0; v < kV; ++v) {
      float coef = ha[v * kV + w];
#pragma unroll
      for (int i = 0; i < 8; ++i) acc[i] += coef * xs[v][cc + i];
    }
    union { uint2 u[2]; bf16 b[8]; } pk;
#pragma unroll
    for (int i = 0; i < 8; ++i) pk.b[i] = __float2bfloat16(acc[i]);
    *reinterpret_cast<uint2*>(XB + obase + w * kDim + cc) = pk.u[0];
    *reinterpret_cast<uint2*>(XB + obase + w * kDim + cc + 4) = pk.u[1];
  }
}

// ---- MFMA GEMM: out[n][p][o] += A[o][k] * B[n][p][k], all k-contiguous -----
// 1 wave/block, 64x64 tile, 16 frags, no LDS (fragments direct from L1/L2).
__global__ void __launch_bounds__(64) mfma_gemm_kernel(
    const bf16* __restrict__ A, const bf16* __restrict__ B,
    bf16* __restrict__ out, int M) {
  const int l = threadIdx.x;
  const int pb = blockIdx.x * 64;
  const int ob = blockIdx.y * 64;
  const int n = blockIdx.z;
  B += (size_t)n * kNCstride;
  out += (size_t)n * kP * M;
  f32x4 acc[4][4] = {};
  const int lm = l & 15;
  const int lk = (l >> 4) * 8;
  for (int kb = 0; kb < kDim; kb += 32) {
    bf16x8 af[4], bfv[4];
#pragma unroll
    for (int mf = 0; mf < 4; ++mf)
      af[mf] = *reinterpret_cast<const bf16x8*>(
          A + (size_t)(ob + mf * 16 + lm) * kDim + kb + lk);
#pragma unroll
    for (int nf = 0; nf < 4; ++nf)
      bfv[nf] = *reinterpret_cast<const bf16x8*>(
          B + (size_t)(pb + nf * 16 + lm) * kDim + kb + lk);
#pragma unroll
    for (int mf = 0; mf < 4; ++mf)
#pragma unroll
      for (int nf = 0; nf < 4; ++nf)
        acc[mf][nf] = __builtin_amdgcn_mfma_f32_16x16x32_bf16(
            af[mf], bfv[nf], acc[mf][nf], 0, 0, 0);
  }
  const int r0 = (l >> 4) * 4;
#pragma unroll
  for (int mf = 0; mf < 4; ++mf) {
    const int o0 = ob + mf * 16 + r0;
#pragma unroll
    for (int nf = 0; nf < 4; ++nf) {
      const int p = pb + nf * 16 + lm;
      union { uint2 u; bf16 b[4]; } pk;
#pragma unroll
      for (int r = 0; r < 4; ++r) pk.b[r] = __float2bfloat16(acc[mf][nf][r]);
      *reinterpret_cast<uint2*>(out + (size_t)p * M + o0) = pk.u;
    }
  }
}

// ---------------- s[n,t] = mean over (c,v) of OP (p-major layout) -----------
__global__ void __launch_bounds__(64) sred_kernel(const bf16* __restrict__ OP,
                                                  float* __restrict__ s) {
  int nt = blockIdx.x, lane = threadIdx.x;
  const uint2* base = reinterpret_cast<const uint2*>(OP + (size_t)nt * kV * kDim);
  float sum = 0.f;
  for (int j = lane; j < kV * kDim / 4; j += 64) {
    union { uint2 u; bf16 b[4]; } tt;
    tt.u = base[j];
    sum += __bfloat162float(tt.b[0]) + __bfloat162float(tt.b[1]) +
           __bfloat162float(tt.b[2]) + __bfloat162float(tt.b[3]);
  }
  for (int off = 32; off > 0; off >>= 1) sum += __shfl_down(sum, off);
  if (lane == 0) s[nt] = sum * (1.f / (kDim * kV));
}

// ---------------- SE gate MLP -> factor f[n,t] = 1 + 0.4*sigmoid(...) -------
__global__ void gate_kernel(const float* __restrict__ s,
                            const float* __restrict__ w1l,
                            const float* __restrict__ b1,
                            const float* __restrict__ w2l,
                            const float* __restrict__ b2,
                            float* __restrict__ gatef) {
  __shared__ float sh[kT];
  __shared__ float hid[12];
  int n = blockIdx.x, t = threadIdx.x;
  sh[t] = s[n * kT + t];
  __syncthreads();
  if (t < 12) {
    float a = b1[t];
    for (int j = 0; j < kT; ++j) a += sh[j] * w1l[t * kT + j];
    hid[t] = fmaxf(a, 0.f);
  }
  __syncthreads();
  float a = b2[t];
  for (int j = 0; j < 12; ++j) a += hid[j] * w2l[t * 12 + j];
  float g = 1.f / (1.f + __expf(-a));
  gatef[n * kT + t] = 1.f + kCoeff * g;
}

// ------- attention per (n,t,h): scores, softmax, PV, grouped proj, residual -
__global__ void __launch_bounds__(256) attn_kernel(
    const bf16* __restrict__ QKV, const bf16* __restrict__ OP,
    const float* __restrict__ gatef, const int* __restrict__ hops,
    const float* __restrict__ rpe, int n_hop, const float* __restrict__ w1,
    const float* __restrict__ outer, const float* __restrict__ alpha_p,
    const float* __restrict__ proj_w, const float* __restrict__ proj_b,
    const float* __restrict__ x, float* __restrict__ out) {
  __shared__ float qs[kV * 33], ks[kV * 33], es[kV * 33], vs[kV * 33],
      os[kV * 33];
  __shared__ float rpe_s[kV * 33];
  __shared__ float sc[kV * 26];
  __shared__ float outer_s[kV * kV];
  __shared__ int hops_s[kV * kV];
  __shared__ float dterm[kV];
  __shared__ float pw[kHd * 33];
  const int tid = threadIdx.x;
  const int b = blockIdx.x;
  const int h = b % kH;
  const int nt = b / kH;
  const int t = nt % kT;
  const int n = nt / kT;
  const float f = gatef[nt];
  const float alpha = alpha_p[0];
  const size_t qb = ((size_t)n * kP + t * kV) * (3 * kDim) + h * kHd;
  const size_t eb = ((size_t)n * kP + t * kV) * kDim + h * kHd;
  if (tid < 200) {
    int v = tid >> 3, dc = (tid & 7) * 4;
    union { uint2 u; bf16 bb[4]; } tq, tk, tv, te;
    tq.u = *reinterpret_cast<const uint2*>(QKV + qb + v * (3 * kDim) + dc);
    tk.u = *reinterpret_cast<const uint2*>(QKV + qb + v * (3 * kDim) + kDim + dc);
    tv.u = *reinterpret_cast<const uint2*>(QKV + qb + v * (3 * kDim) + 2 * kDim + dc);
    te.u = *reinterpret_cast<const uint2*>(OP + eb + v * kDim + dc);
#pragma unroll
    for (int i = 0; i < 4; ++i) {
      qs[v * 33 + dc + i] = __bfloat162float(tq.bb[i]);
      ks[v * 33 + dc + i] = __bfloat162float(tk.bb[i]);
      vs[v * 33 + dc + i] = __bfloat162float(tv.bb[i]);
      es[v * 33 + dc + i] = __bfloat162float(te.bb[i]) * f;
    }
  }
  for (int idx = tid; idx < n_hop * kHd; idx += 256) {
    int hp = idx >> 5, d = idx & 31;
    rpe_s[hp * 33 + d] = rpe[hp * kDim + h * kHd + d];
  }
  for (int idx = tid; idx < kV * kV; idx += 256) {
    hops_s[idx] = hops[idx];
    outer_s[idx] = outer[h * kV * kV + idx];
  }
  for (int idx = tid; idx < kHd * kHd; idx += 256) {
    int oo = idx >> 5, i = idx & 31;
    pw[oo * 33 + i] = proj_w[(h * kHd + oo) * kHd + i];
  }
  __syncthreads();
  if (tid < kV) {
    float a = 0.f;
#pragma unroll
    for (int d = 0; d < kHd; ++d) a += w1[h * kHd + d] * es[tid * 33 + d];
    dterm[tid] = a;
  }
  __syncthreads();
  // scores: (q . (k + e + rpe[hop])) + dterm, scaled
  for (int idx = tid; idx < kV * kV; idx += 256) {
    int v = idx / kV, ww = idx - v * kV;
    int hp = hops_s[idx];
    float a = dterm[ww];
    const float* qv = &qs[v * 33];
    const float* kw = &ks[ww * 33];
    const float* ew = &es[ww * 33];
    const float* rp = &rpe_s[hp * 33];
#pragma unroll
    for (int d = 0; d < kHd; ++d) a += qv[d] * (kw[d] + ew[d] + rp[d]);
    sc[v * 26 + ww] = a * kScale;
  }
  __syncthreads();
  // softmax rows, then p = alpha*attn + outer
  if (tid < kV) {
    float m = -1e30f;
    for (int ww = 0; ww < kV; ++ww) m = fmaxf(m, sc[tid * 26 + ww]);
    float ssum = 0.f;
    for (int ww = 0; ww < kV; ++ww) {
      float e = __expf(sc[tid * 26 + ww] - m);
      sc[tid * 26 + ww] = e;
      ssum += e;
    }
    float inv = alpha / ssum;
    for (int ww = 0; ww < kV; ++ww)
      sc[tid * 26 + ww] = sc[tid * 26 + ww] * inv + outer_s[tid * kV + ww];
  }
  __syncthreads();
  // o = p @ v
  for (int idx = tid; idx < kV * kHd; idx += 256) {
    int v = idx >> 5, d = idx & 31;
    float a = 0.f;
#pragma unroll
    for (int ww = 0; ww < kV; ++ww) a += sc[v * 26 + ww] * vs[ww * 33 + d];
    os[v * 33 + d] = a;
  }
  __syncthreads();
  // grouped 32x32 projection + bias + residual, write final output
  for (int idx = tid; idx < kV * kHd; idx += 256) {
    int oo = idx / kV, v = idx - oo * kV;
    float a = proj_b[h * kHd + oo];
#pragma unroll
    for (int i = 0; i < kHd; ++i) a += pw[oo * 33 + i] * os[v * 33 + i];
    size_t oaddr =
        (size_t)n * kNCstride + (size_t)(h * kHd + oo) * kP + t * kV + v;
    out[oaddr] = x[oaddr] + a;
  }
}

extern "C" void kernel_launch(void* const* d_in, const int* in_sizes, int n_in,
                              void* d_out, int out_size, void* d_ws,
                              size_t ws_size, hipStream_t stream) {
  const float* x = (const float*)d_in[0];
  const int* joint_label = (const int*)d_in[1];
  const float* he_weight = (const float*)d_in[3];
  const int* hops = (const int*)d_in[4];
  const float* ln_g = (const float*)d_in[5];
  const float* ln_b = (const float*)d_in[6];
  const float* hgc_w = (const float*)d_in[7];
  const float* q_w = (const float*)d_in[8];
  const float* kv_w = (const float*)d_in[9];
  const float* proj_w = (const float*)d_in[10];
  const float* proj_b = (const float*)d_in[11];
  const float* rpe = (const float*)d_in[12];
  const float* w1 = (const float*)d_in[13];
  const float* outer = (const float*)d_in[14];
  const float* alpha = (const float*)d_in[15];
  const float* lin1_w = (const float*)d_in[16];
  const float* lin1_b = (const float*)d_in[17];
  const float* lin2_w = (const float*)d_in[18];
  const float* lin2_b = (const float*)d_in[19];
  const int n_hop = in_sizes[12] / kDim;

  // workspace layout (QKV region aliases XB, which dies after hgc GEMM)
  char* w = (char*)d_ws;
  bf16* QKV = (bf16*)w;                       // [n][p][576], 118 MB
  bf16* XB = (bf16*)w;                        // [n][p][192], first 39.3 MB
  w += (size_t)kN * kP * 3 * kDim * 2;
  bf16* XL = (bf16*)w;                        // [n][p][192], 39.3 MB
  w += (size_t)kN * kP * kDim * 2;
  bf16* OP = (bf16*)w;                        // [n][p][192], 39.3 MB
  w += (size_t)kN * kP * kDim * 2;
  bf16* Wb = (bf16*)w;                        // 768x192 bf16
  w += (size_t)768 * kDim * 2;
  float* hadj = (float*)w;
  w += 1024 * 4;
  float* s_ws = (float*)w;
  w += kN * kT * 4;
  float* gatef = (float*)w;
  w += kN * kT * 4;

  hipLaunchKernelGGL(hadj_kernel, dim3(1), dim3(64), 0, stream, joint_label,
                     he_weight, hadj);
  hipLaunchKernelGGL(wconv_kernel, dim3(576), dim3(256), 0, stream, hgc_w, q_w,
                     kv_w, Wb);
  hipLaunchKernelGGL(prep_kernel, dim3(kT, kN), dim3(256), 0, stream, x, hadj,
                     ln_g, ln_b, XB, XL);
  // OP[n][p][o] = hgc_w @ z   (reads XB — must precede QKV GEMM which
  // overwrites the aliased region)
  hipLaunchKernelGGL(mfma_gemm_kernel, dim3(25, 3, kN), dim3(64), 0, stream, Wb,
                     XB, OP, kDim);
  hipLaunchKernelGGL(sred_kernel, dim3(kN * kT), dim3(64), 0, stream, OP, s_ws);
  hipLaunchKernelGGL(gate_kernel, dim3(kN), dim3(kT), 0, stream, s_ws, lin1_w,
                     lin1_b, lin2_w, lin2_b, gatef);
  // QKV[n][p][o] = [q_w; kv_w] @ LN(x)
  hipLaunchKernelGGL(mfma_gemm_kernel, dim3(25, 9, kN), dim3(64), 0, stream,
                     Wb + 192 * kDim, XL, QKV, 3 * kDim);
  hipLaunchKernelGGL(attn_kernel, dim3(kN * kT * kH), dim3(256), 0, stream, QKV,
                     OP, gatef, hops, rpe, n_hop, w1, outer, alpha, proj_w,
                     proj_b, x, (float*)d_out);
}

// Round 3
// 451.739 us; speedup vs baseline: 3.3417x; 1.3790x over previous
//
#include <hip/hip_runtime.h>
#include <hip/hip_bf16.h>

using bf16 = __hip_bfloat16;
typedef __bf16 bf16x8 __attribute__((ext_vector_type(8)));
typedef float f32x4 __attribute__((ext_vector_type(4)));

constexpr int kDim = 192;
constexpr int kH = 6;
constexpr int kHd = 32;
constexpr int kN = 64;
constexpr int kT = 64;
constexpr int kV = 25;
constexpr int kP = kT * kV;            // 1600 positions per n
constexpr int kNCstride = kDim * kP;   // 307200, per-n stride of (c,t,v)
constexpr float kScale = 0.17677669529663687f;  // 32^-0.5
constexpr float kCoeff = 0.4f;

// ---------------- h_adj (25x25) from joint labels ----------------
__global__ void hadj_kernel(const int* __restrict__ jl,
                            const float* __restrict__ hew,
                            float* __restrict__ hadj) {
  __shared__ int lbl[kV];
  __shared__ int cnt[8];
  int t = threadIdx.x;
  if (t < 8) cnt[t] = 0;
  __syncthreads();
  if (t < kV) { lbl[t] = jl[t]; atomicAdd(&cnt[lbl[t]], 1); }
  __syncthreads();
  for (int idx = t; idx < kV * kV; idx += 64) {
    int v = idx / kV, w = idx - v * kV;
    float val = 0.f;
    if (lbl[v] == lbl[w]) val = hew[lbl[v]] / (float)cnt[lbl[v]];
    hadj[idx] = val;
  }
}

// ---------------- weights fp32 -> bf16, combined [hgc;q;kv] 768x192 ---------
__global__ void wconv_kernel(const float* __restrict__ hgc,
                             const float* __restrict__ qw,
                             const float* __restrict__ kvw,
                             bf16* __restrict__ Wb) {
  int i = blockIdx.x * 256 + threadIdx.x;  // 768*192 = 147456 exact
  float v;
  if (i < 36864) v = hgc[i];
  else if (i < 73728) v = qw[i - 36864];
  else v = kvw[i - 73728];
  Wb[i] = __float2bfloat16(v);
}

// ------------- pack rpe (per-h, hop-row, bf16, zero-padded) and proj_w ------
__global__ void pack_kernel(const float* __restrict__ rpe,
                            const float* __restrict__ proj_w, int n_hop,
                            bf16* __restrict__ RPEb, bf16* __restrict__ pwb) {
  int tid = threadIdx.x;
  for (int i = tid; i < kH * 16 * kHd; i += 256) {
    int h = i >> 9, hp = (i >> 5) & 15, d = i & 31;
    float v = (hp < n_hop) ? rpe[hp * kDim + h * kHd + d] : 0.f;
    RPEb[i] = __float2bfloat16(v);
  }
  for (int i = tid; i < kDim * kHd; i += 256)
    pwb[i] = __float2bfloat16(proj_w[i]);
}

// ------- prep per (n,t): stage x slab, LN stats, h_adj apply, emit bf16 -----
__global__ void __launch_bounds__(256) prep_kernel(
    const float* __restrict__ x, const float* __restrict__ hadjg,
    const float* __restrict__ lng, const float* __restrict__ lnb,
    bf16* __restrict__ XB, bf16* __restrict__ XL) {
  __shared__ float xs[kV][193];
  __shared__ float ha[kV * kV];
  __shared__ float ps[kV][8], ps2[kV][8];
  __shared__ float mus[kV], rsd[kV];
  const int tid = threadIdx.x;
  const int t = blockIdx.x, n = blockIdx.y;
  for (int i = tid; i < kV * kV; i += 256) ha[i] = hadjg[i];
  const float* xb = x + (size_t)n * kNCstride + t * kV;
  for (int idx = tid; idx < kDim * kV; idx += 256) {
    int c = idx / kV, p = idx - c * kV;
    xs[p][c] = xb[(size_t)c * kP + p];
  }
  __syncthreads();
  if (tid < 200) {
    int p = tid >> 3, q = tid & 7;
    float a = 0.f, b = 0.f;
    int c0 = q * 24;
    for (int c = c0; c < c0 + 24; ++c) { float v = xs[p][c]; a += v; b += v * v; }
    ps[p][q] = a; ps2[p][q] = b;
  }
  __syncthreads();
  if (tid < kV) {
    float a = 0.f, b = 0.f;
    for (int q = 0; q < 8; ++q) { a += ps[tid][q]; b += ps2[tid][q]; }
    float m = a * (1.f / kDim);
    float var = b * (1.f / kDim) - m * m;
    mus[tid] = m; rsd[tid] = rsqrtf(var + 1e-5f);
  }
  __syncthreads();
  size_t obase = ((size_t)n * kP + t * kV) * kDim;
  for (int idx = tid; idx < 600; idx += 256) {
    int p = idx / 24, cc = (idx - p * 24) * 8;
    float m = mus[p], r = rsd[p];
    union { uint2 u[2]; bf16 b[8]; } pk;
#pragma unroll
    for (int i = 0; i < 8; ++i) {
      int c = cc + i;
      pk.b[i] = __float2bfloat16((xs[p][c] - m) * r * lng[c] + lnb[c]);
    }
    *reinterpret_cast<uint2*>(XL + obase + p * kDim + cc) = pk.u[0];
    *reinterpret_cast<uint2*>(XL + obase + p * kDim + cc + 4) = pk.u[1];
  }
  for (int idx = tid; idx < 600; idx += 256) {
    int w = idx / 24, cc = (idx - w * 24) * 8;
    float acc[8] = {0.f, 0.f, 0.f, 0.f, 0.f, 0.f, 0.f, 0.f};
    for (int v = 0; v < kV; ++v) {
      float coef = ha[v * kV + w];
#pragma unroll
      for (int i = 0; i < 8; ++i) acc[i] += coef * xs[v][cc + i];
    }
    union { uint2 u[2]; bf16 b[8]; } pk;
#pragma unroll
    for (int i = 0; i < 8; ++i) pk.b[i] = __float2bfloat16(acc[i]);
    *reinterpret_cast<uint2*>(XB + obase + w * kDim + cc) = pk.u[0];
    *reinterpret_cast<uint2*>(XB + obase + w * kDim + cc + 4) = pk.u[1];
  }
}

// ---- MFMA GEMM: out[n][p][o] = A[o][k]*B[n][p][k], XCD-chunked swizzle -----
__global__ void __launch_bounds__(64) mfma_gemm_kernel(
    const bf16* __restrict__ A, const bf16* __restrict__ B,
    bf16* __restrict__ out, int M, int obn) {
  int id = blockIdx.x;
  int per = gridDim.x >> 3;  // grid % 8 == 0
  int wg = (id & 7) * per + (id >> 3);
  int n = wg / (25 * obn);
  int rem = wg - n * (25 * obn);
  const int ob = (rem / 25) * 64;
  const int pb = (rem % 25) * 64;
  const int l = threadIdx.x;
  B += (size_t)n * kNCstride;
  out += (size_t)n * kP * M;
  f32x4 acc[4][4] = {};
  const int lm = l & 15;
  const int lk = (l >> 4) * 8;
  for (int kb = 0; kb < kDim; kb += 32) {
    bf16x8 af[4], bfv[4];
#pragma unroll
    for (int mf = 0; mf < 4; ++mf)
      af[mf] = *reinterpret_cast<const bf16x8*>(
          A + (size_t)(ob + mf * 16 + lm) * kDim + kb + lk);
#pragma unroll
    for (int nf = 0; nf < 4; ++nf)
      bfv[nf] = *reinterpret_cast<const bf16x8*>(
          B + (size_t)(pb + nf * 16 + lm) * kDim + kb + lk);
#pragma unroll
    for (int mf = 0; mf < 4; ++mf)
#pragma unroll
      for (int nf = 0; nf < 4; ++nf)
        acc[mf][nf] = __builtin_amdgcn_mfma_f32_16x16x32_bf16(
            af[mf], bfv[nf], acc[mf][nf], 0, 0, 0);
  }
  const int r0 = (l >> 4) * 4;
#pragma unroll
  for (int mf = 0; mf < 4; ++mf) {
    const int o0 = ob + mf * 16 + r0;
#pragma unroll
    for (int nf = 0; nf < 4; ++nf) {
      const int p = pb + nf * 16 + lm;
      union { uint2 u; bf16 b[4]; } pk;
#pragma unroll
      for (int r = 0; r < 4; ++r) pk.b[r] = __float2bfloat16(acc[mf][nf][r]);
      *reinterpret_cast<uint2*>(out + (size_t)p * M + o0) = pk.u;
    }
  }
}

// ---------------- s[n,t] = mean over (c,v) of OP (p-major layout) -----------
__global__ void __launch_bounds__(64) sred_kernel(const bf16* __restrict__ OP,
                                                  float* __restrict__ s) {
  int nt = blockIdx.x, lane = threadIdx.x;
  const uint2* base = reinterpret_cast<const uint2*>(OP + (size_t)nt * kV * kDim);
  float sum = 0.f;
  for (int j = lane; j < kV * kDim / 4; j += 64) {
    union { uint2 u; bf16 b[4]; } tt;
    tt.u = base[j];
    sum += __bfloat162float(tt.b[0]) + __bfloat162float(tt.b[1]) +
           __bfloat162float(tt.b[2]) + __bfloat162float(tt.b[3]);
  }
  for (int off = 32; off > 0; off >>= 1) sum += __shfl_down(sum, off);
  if (lane == 0) s[nt] = sum * (1.f / (kDim * kV));
}

// ---------------- SE gate MLP -> factor f[n,t] = 1 + 0.4*sigmoid(...) -------
__global__ void gate_kernel(const float* __restrict__ s,
                            const float* __restrict__ w1l,
                            const float* __restrict__ b1,
                            const float* __restrict__ w2l,
                            const float* __restrict__ b2,
                            float* __restrict__ gatef) {
  __shared__ float sh[kT];
  __shared__ float hid[12];
  int n = blockIdx.x, t = threadIdx.x;
  sh[t] = s[n * kT + t];
  __syncthreads();
  if (t < 12) {
    float a = b1[t];
    for (int j = 0; j < kT; ++j) a += sh[j] * w1l[t * kT + j];
    hid[t] = fmaxf(a, 0.f);
  }
  __syncthreads();
  float a = b2[t];
  for (int j = 0; j < 12; ++j) a += hid[j] * w2l[t * 12 + j];
  float g = 1.f / (1.f + __expf(-a));
  gatef[n * kT + t] = 1.f + kCoeff * g;
}

// ---------- MFMA attention: block = (n,t), 6 waves, wave = head ------------
__global__ void __launch_bounds__(384) attn_kernel(
    const bf16* __restrict__ QKV, const bf16* __restrict__ OP,
    const float* __restrict__ gatef, const int* __restrict__ hops,
    const bf16* __restrict__ RPEb, const float* __restrict__ w1,
    const float* __restrict__ outer, const float* __restrict__ alpha_p,
    const bf16* __restrict__ pwb, const float* __restrict__ proj_b,
    const float* __restrict__ x, float* __restrict__ out) {
  // per-wave LDS: Vt[32][40] | P[32][40] | (QR[32][16]f32 alias O[32][40])
  __shared__ ushort wls[kH][3840];
  __shared__ int hopsS[kV][32];
  const int tid = threadIdx.x;
  const int lane = tid & 63;
  const int h = tid >> 6;  // wave id = head
  const int t = blockIdx.x, n = blockIdx.y;
  const int nt = n * kT + t;
  const int lm = lane & 15, g = lane >> 4;

  for (int i = tid; i < kV * 32; i += 384) {
    int v = i >> 5, w = i & 31;
    hopsS[v][w] = (w < kV) ? hops[v * kV + w] : 0;
  }
  __syncthreads();

  bf16* Vt = (bf16*)&wls[h][0];       // [32][40]
  bf16* Pp = (bf16*)&wls[h][1280];    // [32][40]
  bf16* OLp = (bf16*)&wls[h][2560];   // [32][40]
  float* QRp = (float*)&wls[h][2560]; // [32][16] (alias, used before OLp)

  const float f = gatef[nt];
  const float alpha = alpha_p[0];
  const bf16* Qbase = QKV + (size_t)(n * kP + t * kV) * 576;
  const bf16* Ebase = OP + (size_t)(n * kP + t * kV) * kDim;
  const int colO = h * kHd + g * 8;

  // ---- fragment loads (direct from global, k-contiguous 16B) ----
  bf16x8 qf[2], kf[2], ef[2];
#pragma unroll
  for (int mf = 0; mf < 2; ++mf) {
    const bf16* row = Qbase + (size_t)(mf * 16 + lm) * 576;
    qf[mf] = *reinterpret_cast<const bf16x8*>(row + colO);
    kf[mf] = *reinterpret_cast<const bf16x8*>(row + kDim + colO);
    ef[mf] = *reinterpret_cast<const bf16x8*>(
        Ebase + (size_t)(mf * 16 + lm) * kDim + h * kHd + g * 8);
  }
  bf16x8 rf = *reinterpret_cast<const bf16x8*>(RPEb + (h * 16 + lm) * kHd + g * 8);

  // ---- d-term from raw E frags: dt[nf] = f * sum_d w1[h,d]*e[w,d] ----
  float w1v[8];
  {
    float4 wa = *reinterpret_cast<const float4*>(w1 + h * kHd + g * 8);
    float4 wb = *reinterpret_cast<const float4*>(w1 + h * kHd + g * 8 + 4);
    w1v[0] = wa.x; w1v[1] = wa.y; w1v[2] = wa.z; w1v[3] = wa.w;
    w1v[4] = wb.x; w1v[5] = wb.y; w1v[6] = wb.z; w1v[7] = wb.w;
  }
  float dt[2];
#pragma unroll
  for (int nf = 0; nf < 2; ++nf) {
    float a = 0.f;
#pragma unroll
    for (int j = 0; j < 8; ++j) a += w1v[j] * (float)ef[nf][j];
    a += __shfl_xor(a, 16);
    a += __shfl_xor(a, 32);
    dt[nf] = f * a;
  }

  // ---- fold gate into K: ke = k + f*e (bf16) ----
  bf16x8 kef[2];
#pragma unroll
  for (int nf = 0; nf < 2; ++nf)
#pragma unroll
    for (int j = 0; j < 8; ++j)
      kef[nf][j] = (__bf16)((float)kf[nf][j] + f * (float)ef[nf][j]);

  // ---- V transpose staging into LDS (Vt[d][w]) + zero pad cols ----
#pragma unroll
  for (int i = lane; i < 32 * 8; i += 64) {
    int d = i >> 3, w = 24 + (i & 7);
    Vt[d * 40 + w] = __float2bfloat16(0.f);
  }
  for (int i = lane; i < 200; i += 64) {
    int v = i >> 3, dq = i & 7;
    union { uint2 u; bf16 b[4]; } ld;
    ld.u = *reinterpret_cast<const uint2*>(Qbase + (size_t)v * 576 + 384 +
                                           h * kHd + dq * 4);
#pragma unroll
    for (int j = 0; j < 4; ++j) Vt[(dq * 4 + j) * 40 + v] = ld.b[j];
  }

  // ---- S = Q(KE)^T and QR = Q rpe^T via MFMA ----
  f32x4 aK[2][2] = {};
  f32x4 aR[2] = {};
#pragma unroll
  for (int mf = 0; mf < 2; ++mf) {
#pragma unroll
    for (int nf = 0; nf < 2; ++nf)
      aK[mf][nf] =
          __builtin_amdgcn_mfma_f32_16x16x32_bf16(qf[mf], kef[nf], aK[mf][nf], 0, 0, 0);
    aR[mf] = __builtin_amdgcn_mfma_f32_16x16x32_bf16(qf[mf], rf, aR[mf], 0, 0, 0);
  }

  // dump QR to LDS: QR[v][hp]
#pragma unroll
  for (int mf = 0; mf < 2; ++mf)
#pragma unroll
    for (int r = 0; r < 4; ++r)
      QRp[(mf * 16 + g * 4 + r) * 16 + lm] = aR[mf][r];

  // ---- epilogue: bias-gather + softmax (register butterfly) + P write ----
  const bool w1ok = (lm + 16) < kV;
#pragma unroll
  for (int mf = 0; mf < 2; ++mf) {
#pragma unroll
    for (int r = 0; r < 4; ++r) {
      int v = mf * 16 + g * 4 + r;
      int vc = v < kV ? v : kV - 1;
      int hp0 = hopsS[vc][lm];
      int hp1 = hopsS[vc][lm + 16];
      float s0 = (aK[mf][0][r] + QRp[v * 16 + hp0] + dt[0]) * kScale;
      float s1 = (aK[mf][1][r] + QRp[v * 16 + hp1] + dt[1]) * kScale;
      if (!w1ok) s1 = -3.0e38f;
      float m = fmaxf(s0, s1);
#pragma unroll
      for (int d = 1; d < 16; d <<= 1) m = fmaxf(m, __shfl_xor(m, d));
      float e0 = __expf(s0 - m);
      float e1 = w1ok ? __expf(s1 - m) : 0.f;
      float sum = e0 + e1;
#pragma unroll
      for (int d = 1; d < 16; d <<= 1) sum += __shfl_xor(sum, d);
      float inv = alpha / sum;
      float o0 = outer[h * (kV * kV) + vc * kV + lm];
      float o1 = w1ok ? outer[h * (kV * kV) + vc * kV + lm + 16] : 0.f;
      Pp[v * 40 + lm] = __float2bfloat16(e0 * inv + o0);
      Pp[v * 40 + lm + 16] = __float2bfloat16(w1ok ? e1 * inv + o1 : 0.f);
    }
  }

  // ---- PV: O[v][d] = P @ V ----
  bf16x8 pa[2], vb[2];
#pragma unroll
  for (int mf = 0; mf < 2; ++mf)
    pa[mf] = *reinterpret_cast<const bf16x8*>(Pp + (mf * 16 + lm) * 40 + g * 8);
#pragma unroll
  for (int nf = 0; nf < 2; ++nf)
    vb[nf] = *reinterpret_cast<const bf16x8*>(Vt + (nf * 16 + lm) * 40 + g * 8);
  f32x4 aO[2][2] = {};
#pragma unroll
  for (int mf = 0; mf < 2; ++mf)
#pragma unroll
    for (int nf = 0; nf < 2; ++nf)
      aO[mf][nf] =
          __builtin_amdgcn_mfma_f32_16x16x32_bf16(pa[mf], vb[nf], aO[mf][nf], 0, 0, 0);

  // ---- O -> LDS (bf16), then grouped proj via MFMA ----
#pragma unroll
  for (int mf = 0; mf < 2; ++mf)
#pragma unroll
    for (int nf = 0; nf < 2; ++nf)
#pragma unroll
      for (int r = 0; r < 4; ++r)
        OLp[(mf * 16 + g * 4 + r) * 40 + nf * 16 + lm] =
            __float2bfloat16(aO[mf][nf][r]);

  bf16x8 oa[2], pwf[2];
#pragma unroll
  for (int mf = 0; mf < 2; ++mf)
    oa[mf] = *reinterpret_cast<const bf16x8*>(OLp + (mf * 16 + lm) * 40 + g * 8);
#pragma unroll
  for (int nf = 0; nf < 2; ++nf)
    pwf[nf] = *reinterpret_cast<const bf16x8*>(pwb +
        (h * kHd + nf * 16 + lm) * kHd + g * 8);
  f32x4 aF[2][2] = {};
#pragma unroll
  for (int mf = 0; mf < 2; ++mf)
#pragma unroll
    for (int nf = 0; nf < 2; ++nf)
      aF[mf][nf] =
          __builtin_amdgcn_mfma_f32_16x16x32_bf16(oa[mf], pwf[nf], aF[mf][nf], 0, 0, 0);

  // ---- bias + residual scatter store into [n][c][t][v] ----
  float pb0 = proj_b[h * kHd + lm];
  float pb1 = proj_b[h * kHd + 16 + lm];
#pragma unroll
  for (int mf = 0; mf < 2; ++mf) {
#pragma unroll
    for (int r = 0; r < 4; ++r) {
      int v = mf * 16 + g * 4 + r;
      if (v < kV) {
#pragma unroll
        for (int nf = 0; nf < 2; ++nf) {
          int oo = nf * 16 + lm;
          size_t ga = (size_t)n * kNCstride + (size_t)(h * kHd + oo) * kP +
                      t * kV + v;
          out[ga] = x[ga] + aF[mf][nf][r] + (nf ? pb1 : pb0);
        }
      }
    }
  }
}

extern "C" void kernel_launch(void* const* d_in, const int* in_sizes, int n_in,
                              void* d_out, int out_size, void* d_ws,
                              size_t ws_size, hipStream_t stream) {
  const float* x = (const float*)d_in[0];
  const int* joint_label = (const int*)d_in[1];
  const float* he_weight = (const float*)d_in[3];
  const int* hops = (const int*)d_in[4];
  const float* ln_g = (const float*)d_in[5];
  const float* ln_b = (const float*)d_in[6];
  const float* hgc_w = (const float*)d_in[7];
  const float* q_w = (const float*)d_in[8];
  const float* kv_w = (const float*)d_in[9];
  const float* proj_w = (const float*)d_in[10];
  const float* proj_b = (const float*)d_in[11];
  const float* rpe = (const float*)d_in[12];
  const float* w1 = (const float*)d_in[13];
  const float* outer = (const float*)d_in[14];
  const float* alpha = (const float*)d_in[15];
  const float* lin1_w = (const float*)d_in[16];
  const float* lin1_b = (const float*)d_in[17];
  const float* lin2_w = (const float*)d_in[18];
  const float* lin2_b = (const float*)d_in[19];
  const int n_hop = in_sizes[12] / kDim;

  // workspace layout (QKV region aliases XB, which dies after hgc GEMM)
  char* w = (char*)d_ws;
  bf16* QKV = (bf16*)w;                       // [n][p][576], 118 MB
  bf16* XB = (bf16*)w;                        // [n][p][192], first 39.3 MB
  w += (size_t)kN * kP * 3 * kDim * 2;
  bf16* XL = (bf16*)w;                        // [n][p][192]
  w += (size_t)kN * kP * kDim * 2;
  bf16* OP = (bf16*)w;                        // [n][p][192]
  w += (size_t)kN * kP * kDim * 2;
  w += 65536;                                 // tail slack for padded-row reads
  bf16* Wb = (bf16*)w;                        // 768x192 bf16
  w += (size_t)768 * kDim * 2;
  bf16* RPEb = (bf16*)w;                      // [6][16][32] bf16
  w += (size_t)kH * 16 * kHd * 2;
  bf16* pwb = (bf16*)w;                       // [192][32] bf16
  w += (size_t)kDim * kHd * 2;
  float* hadj = (float*)w;
  w += 1024 * 4;
  float* s_ws = (float*)w;
  w += kN * kT * 4;
  float* gatef = (float*)w;
  w += kN * kT * 4;

  hipLaunchKernelGGL(hadj_kernel, dim3(1), dim3(64), 0, stream, joint_label,
                     he_weight, hadj);
  hipLaunchKernelGGL(wconv_kernel, dim3(576), dim3(256), 0, stream, hgc_w, q_w,
                     kv_w, Wb);
  hipLaunchKernelGGL(pack_kernel, dim3(1), dim3(256), 0, stream, rpe, proj_w,
                     n_hop, RPEb, pwb);
  hipLaunchKernelGGL(prep_kernel, dim3(kT, kN), dim3(256), 0, stream, x, hadj,
                     ln_g, ln_b, XB, XL);
  // OP[n][p][o] = hgc_w @ z  (before QKV GEMM overwrites aliased XB)
  hipLaunchKernelGGL(mfma_gemm_kernel, dim3(25 * 3 * kN), dim3(64), 0, stream,
                     Wb, XB, OP, kDim, 3);
  hipLaunchKernelGGL(sred_kernel, dim3(kN * kT), dim3(64), 0, stream, OP, s_ws);
  hipLaunchKernelGGL(gate_kernel, dim3(kN), dim3(kT), 0, stream, s_ws, lin1_w,
                     lin1_b, lin2_w, lin2_b, gatef);
  // QKV[n][p][o] = [q_w; kv_w] @ LN(x)
  hipLaunchKernelGGL(mfma_gemm_kernel, dim3(25 * 9 * kN), dim3(64), 0, stream,
                     Wb + 192 * kDim, XL, QKV, 3 * kDim, 9);
  hipLaunchKernelGGL(attn_kernel, dim3(kT, kN), dim3(384), 0, stream, QKV, OP,
                     gatef, hops, RPEb, w1, outer, alpha, pwb, proj_b, x,
                     (float*)d_out);
}

// Round 4
// 435.328 us; speedup vs baseline: 3.4677x; 1.0377x over previous
//
#include <hip/hip_runtime.h>
#include <hip/hip_bf16.h>

using bf16 = __hip_bfloat16;
typedef __bf16 bf16x8 __attribute__((ext_vector_type(8)));
typedef float f32x4 __attribute__((ext_vector_type(4)));

constexpr int kDim = 192;
constexpr int kH = 6;
constexpr int kHd = 32;
constexpr int kN = 64;
constexpr int kT = 64;
constexpr int kV = 25;
constexpr int kP = kT * kV;            // 1600 positions per n
constexpr int kNCstride = kDim * kP;   // 307200, per-n stride of (c,t,v)
constexpr float kScale = 0.17677669529663687f;  // 32^-0.5
constexpr float kCoeff = 0.4f;

// ---- setup: h_adj, weight conversion, rpe/proj packing, VT pad zeroing ----
__global__ void __launch_bounds__(256) setup_kernel(
    const int* __restrict__ jl, const float* __restrict__ hew,
    const float* __restrict__ hgc, const float* __restrict__ qw,
    const float* __restrict__ kvw, const float* __restrict__ rpe,
    const float* __restrict__ proj_w, int n_hop, float* __restrict__ hadj,
    bf16* __restrict__ Wb, bf16* __restrict__ RPEb, bf16* __restrict__ pwb,
    bf16* __restrict__ VT) {
  const int bid = blockIdx.x;
  const int tid = threadIdx.x;
  if (bid < 576) {  // weight fp32->bf16, combined [hgc;q;kv] 768x192
    int i = bid * 256 + tid;
    float v;
    if (i < 36864) v = hgc[i];
    else if (i < 73728) v = qw[i - 36864];
    else v = kvw[i - 73728];
    Wb[i] = __float2bfloat16(v);
  } else if (bid == 576) {  // h_adj from labels
    __shared__ int lbl[kV];
    __shared__ int cnt[8];
    if (tid < 8) cnt[tid] = 0;
    __syncthreads();
    if (tid < kV) { lbl[tid] = jl[tid]; atomicAdd(&cnt[lbl[tid]], 1); }
    __syncthreads();
    for (int idx = tid; idx < kV * kV; idx += 256) {
      int v = idx / kV, w = idx - v * kV;
      float val = 0.f;
      if (lbl[v] == lbl[w]) val = hew[lbl[v]] / (float)cnt[lbl[v]];
      hadj[idx] = val;
    }
  } else if (bid == 577) {  // pack rpe (zero-padded to 16 hops) + proj_w
    for (int i = tid; i < kH * 16 * kHd; i += 256) {
      int h = i >> 9, hp = (i >> 5) & 15, d = i & 31;
      float v = (hp < n_hop) ? rpe[hp * kDim + h * kHd + d] : 0.f;
      RPEb[i] = __float2bfloat16(v);
    }
    for (int i = tid; i < kDim * kHd; i += 256)
      pwb[i] = __float2bfloat16(proj_w[i]);
  } else {  // zero VT pad cols 24..31 (one 16B store per row)
    int row = (bid - 578) * 256 + tid;
    if (row < kN * kT * kDim) {
      uint4 z = {0u, 0u, 0u, 0u};
      *reinterpret_cast<uint4*>(reinterpret_cast<char*>(VT) + (size_t)row * 64 +
                                48) = z;
    }
  }
}

// ------- prep per (n,t): stage x slab, LN stats, h_adj apply, emit bf16 -----
__global__ void __launch_bounds__(256) prep_kernel(
    const float* __restrict__ x, const float* __restrict__ hadjg,
    const float* __restrict__ lng, const float* __restrict__ lnb,
    bf16* __restrict__ XB, bf16* __restrict__ XL) {
  __shared__ float xs[kV][193];
  __shared__ float ha[kV * kV];
  __shared__ float ps[kV][8], ps2[kV][8];
  __shared__ float mus[kV], rsd[kV];
  const int tid = threadIdx.x;
  const int t = blockIdx.x, n = blockIdx.y;
  for (int i = tid; i < kV * kV; i += 256) ha[i] = hadjg[i];
  const float* xb = x + (size_t)n * kNCstride + t * kV;
  for (int idx = tid; idx < kDim * kV; idx += 256) {
    int c = idx / kV, p = idx - c * kV;
    xs[p][c] = xb[(size_t)c * kP + p];
  }
  __syncthreads();
  if (tid < 200) {
    int p = tid >> 3, q = tid & 7;
    float a = 0.f, b = 0.f;
    int c0 = q * 24;
    for (int c = c0; c < c0 + 24; ++c) { float v = xs[p][c]; a += v; b += v * v; }
    ps[p][q] = a; ps2[p][q] = b;
  }
  __syncthreads();
  if (tid < kV) {
    float a = 0.f, b = 0.f;
    for (int q = 0; q < 8; ++q) { a += ps[tid][q]; b += ps2[tid][q]; }
    float m = a * (1.f / kDim);
    float var = b * (1.f / kDim) - m * m;
    mus[tid] = m; rsd[tid] = rsqrtf(var + 1e-5f);
  }
  __syncthreads();
  size_t obase = ((size_t)n * kP + t * kV) * kDim;
  for (int idx = tid; idx < 600; idx += 256) {
    int p = idx / 24, cc = (idx - p * 24) * 8;
    float m = mus[p], r = rsd[p];
    union { uint2 u[2]; bf16 b[8]; } pk;
#pragma unroll
    for (int i = 0; i < 8; ++i) {
      int c = cc + i;
      pk.b[i] = __float2bfloat16((xs[p][c] - m) * r * lng[c] + lnb[c]);
    }
    *reinterpret_cast<uint2*>(XL + obase + p * kDim + cc) = pk.u[0];
    *reinterpret_cast<uint2*>(XL + obase + p * kDim + cc + 4) = pk.u[1];
  }
  for (int idx = tid; idx < 600; idx += 256) {
    int w = idx / 24, cc = (idx - w * 24) * 8;
    float acc[8] = {0.f, 0.f, 0.f, 0.f, 0.f, 0.f, 0.f, 0.f};
    for (int v = 0; v < kV; ++v) {
      float coef = ha[v * kV + w];
#pragma unroll
      for (int i = 0; i < 8; ++i) acc[i] += coef * xs[v][cc + i];
    }
    union { uint2 u[2]; bf16 b[8]; } pk;
#pragma unroll
    for (int i = 0; i < 8; ++i) pk.b[i] = __float2bfloat16(acc[i]);
    *reinterpret_cast<uint2*>(XB + obase + w * kDim + cc) = pk.u[0];
    *reinterpret_cast<uint2*>(XB + obase + w * kDim + cc + 4) = pk.u[1];
  }
}

// ---- MFMA GEMM: out[n][p][o] = A[o][k]*B[n][p][k]; V-part -> VT transposed -
// Logical block order: B-tile-sharing blocks contiguous -> same XCD L2.
template <int OBN, int MOUT, bool VS>
__global__ void __launch_bounds__(64) mfma_gemm_kernel(
    const bf16* __restrict__ A, const bf16* __restrict__ B,
    bf16* __restrict__ out, bf16* __restrict__ VT) {
  int id = blockIdx.x;
  int per = gridDim.x >> 3;  // grid % 8 == 0
  int wg = (id & 7) * per + (id >> 3);
  int n = wg / (25 * OBN);
  int rem = wg - n * (25 * OBN);
  const int pb = (rem / OBN) * 64;
  const int ob = (rem % OBN) * 64;
  const int l = threadIdx.x;
  B += (size_t)n * kNCstride;
  out += (size_t)n * kP * MOUT;
  f32x4 acc[4][4] = {};
  const int lm = l & 15;
  const int lk = (l >> 4) * 8;
  for (int kb = 0; kb < kDim; kb += 32) {
    bf16x8 af[4], bfv[4];
#pragma unroll
    for (int mf = 0; mf < 4; ++mf)
      af[mf] = *reinterpret_cast<const bf16x8*>(
          A + (size_t)(ob + mf * 16 + lm) * kDim + kb + lk);
#pragma unroll
    for (int nf = 0; nf < 4; ++nf)
      bfv[nf] = *reinterpret_cast<const bf16x8*>(
          B + (size_t)(pb + nf * 16 + lm) * kDim + kb + lk);
#pragma unroll
    for (int mf = 0; mf < 4; ++mf)
#pragma unroll
      for (int nf = 0; nf < 4; ++nf)
        acc[mf][nf] = __builtin_amdgcn_mfma_f32_16x16x32_bf16(
            af[mf], bfv[nf], acc[mf][nf], 0, 0, 0);
  }
  const int r0 = (l >> 4) * 4;
  int tt[4], vv[4];
#pragma unroll
  for (int nf = 0; nf < 4; ++nf) {
    int p = pb + nf * 16 + lm;
    tt[nf] = p / 25;
    vv[nf] = p - tt[nf] * 25;
  }
#pragma unroll
  for (int mf = 0; mf < 4; ++mf) {
    const int o0 = ob + mf * 16 + r0;
    if (!VS || o0 < 384) {
#pragma unroll
      for (int nf = 0; nf < 4; ++nf) {
        const int p = pb + nf * 16 + lm;
        union { uint2 u; bf16 b[4]; } pk;
#pragma unroll
        for (int r = 0; r < 4; ++r) pk.b[r] = __float2bfloat16(acc[mf][nf][r]);
        *reinterpret_cast<uint2*>(out + (size_t)p * MOUT + o0) = pk.u;
      }
    } else {  // V third: write transposed VT[(n*64+t)*192 + d][v]
#pragma unroll
      for (int nf = 0; nf < 4; ++nf) {
        size_t rowb =
            ((size_t)(n * kT + tt[nf]) * kDim + (o0 - 384)) * 32 + vv[nf];
#pragma unroll
        for (int r = 0; r < 4; ++r)
          VT[rowb + (size_t)r * 32] = __float2bfloat16(acc[mf][nf][r]);
      }
    }
  }
}

// ---------------- s[n,t] = mean over (c,v) of OP (p-major layout) -----------
__global__ void __launch_bounds__(64) sred_kernel(const bf16* __restrict__ OP,
                                                  float* __restrict__ s) {
  int nt = blockIdx.x, lane = threadIdx.x;
  const uint2* base = reinterpret_cast<const uint2*>(OP + (size_t)nt * kV * kDim);
  float sum = 0.f;
  for (int j = lane; j < kV * kDim / 4; j += 64) {
    union { uint2 u; bf16 b[4]; } tt;
    tt.u = base[j];
    sum += __bfloat162float(tt.b[0]) + __bfloat162float(tt.b[1]) +
           __bfloat162float(tt.b[2]) + __bfloat162float(tt.b[3]);
  }
  for (int off = 32; off > 0; off >>= 1) sum += __shfl_down(sum, off);
  if (lane == 0) s[nt] = sum * (1.f / (kDim * kV));
}

// ---------------- SE gate MLP -> factor f[n,t] = 1 + 0.4*sigmoid(...) -------
__global__ void gate_kernel(const float* __restrict__ s,
                            const float* __restrict__ w1l,
                            const float* __restrict__ b1,
                            const float* __restrict__ w2l,
                            const float* __restrict__ b2,
                            float* __restrict__ gatef) {
  __shared__ float sh[kT];
  __shared__ float hid[12];
  int n = blockIdx.x, t = threadIdx.x;
  sh[t] = s[n * kT + t];
  __syncthreads();
  if (t < 12) {
    float a = b1[t];
    for (int j = 0; j < kT; ++j) a += sh[j] * w1l[t * kT + j];
    hid[t] = fmaxf(a, 0.f);
  }
  __syncthreads();
  float a = b2[t];
  for (int j = 0; j < 12; ++j) a += hid[j] * w2l[t * 12 + j];
  float g = 1.f / (1.f + __expf(-a));
  gatef[n * kT + t] = 1.f + kCoeff * g;
}

// ---------- MFMA attention: block = (n,t), 6 waves, wave = head ------------
__global__ void __launch_bounds__(384) attn_kernel(
    const bf16* __restrict__ QK, const bf16* __restrict__ VT,
    const bf16* __restrict__ OP, const float* __restrict__ gatef,
    const int* __restrict__ hops, const bf16* __restrict__ RPEb,
    const float* __restrict__ w1, const float* __restrict__ outer,
    const float* __restrict__ alpha_p, const bf16* __restrict__ pwb,
    const float* __restrict__ proj_b, const float* __restrict__ x,
    float* __restrict__ out) {
  // per-wave LDS: P[32][40] bf16 | (QR[32][18] f32 alias OL[32][40] bf16)
  __shared__ ushort wls[kH][2560];
  __shared__ int hopsS[kV][32];
  const int tid = threadIdx.x;
  const int lane = tid & 63;
  const int h = tid >> 6;  // wave id = head
  const int t = blockIdx.x, n = blockIdx.y;
  const int nt = n * kT + t;
  const int lm = lane & 15, g = lane >> 4;

  for (int i = tid; i < kV * 32; i += 384) {
    int v = i >> 5, w = i & 31;
    hopsS[v][w] = (w < kV) ? hops[v * kV + w] : 0;
  }
  __syncthreads();

  bf16* Pp = (bf16*)&wls[h][0];       // [32][40]
  bf16* OLp = (bf16*)&wls[h][1280];   // [32][40]
  float* QRp = (float*)&wls[h][1280]; // [32][18] (alias, used before OLp)

  const float f = gatef[nt];
  const float alpha = alpha_p[0];
  const bf16* Qbase = QK + (size_t)(n * kP + t * kV) * 384;
  const bf16* Ebase = OP + (size_t)(n * kP + t * kV) * kDim;
  const int colO = h * kHd + g * 8;

  // ---- fragment loads (direct from global, k-contiguous 16B) ----
  bf16x8 qf[2], kf[2], ef[2];
#pragma unroll
  for (int mf = 0; mf < 2; ++mf) {
    const bf16* row = Qbase + (size_t)(mf * 16 + lm) * 384;
    qf[mf] = *reinterpret_cast<const bf16x8*>(row + colO);
    kf[mf] = *reinterpret_cast<const bf16x8*>(row + kDim + colO);
    ef[mf] = *reinterpret_cast<const bf16x8*>(
        Ebase + (size_t)(mf * 16 + lm) * kDim + colO);
  }
  bf16x8 rf = *reinterpret_cast<const bf16x8*>(RPEb + (h * 16 + lm) * kHd + g * 8);

  // ---- d-term from raw E frags: dt[nf] = f * sum_d w1[h,d]*e[w,d] ----
  float w1v[8];
  {
    float4 wa = *reinterpret_cast<const float4*>(w1 + h * kHd + g * 8);
    float4 wb = *reinterpret_cast<const float4*>(w1 + h * kHd + g * 8 + 4);
    w1v[0] = wa.x; w1v[1] = wa.y; w1v[2] = wa.z; w1v[3] = wa.w;
    w1v[4] = wb.x; w1v[5] = wb.y; w1v[6] = wb.z; w1v[7] = wb.w;
  }
  float dt[2];
#pragma unroll
  for (int nf = 0; nf < 2; ++nf) {
    float a = 0.f;
#pragma unroll
    for (int j = 0; j < 8; ++j) a += w1v[j] * (float)ef[nf][j];
    a += __shfl_xor(a, 16);
    a += __shfl_xor(a, 32);
    dt[nf] = f * a;
  }

  // ---- fold gate into K: ke = k + f*e (bf16) ----
  bf16x8 kef[2];
#pragma unroll
  for (int nf = 0; nf < 2; ++nf)
#pragma unroll
    for (int j = 0; j < 8; ++j)
      kef[nf][j] = (__bf16)((float)kf[nf][j] + f * (float)ef[nf][j]);

  // ---- S = Q(KE)^T and QR = Q rpe^T via MFMA ----
  f32x4 aK[2][2] = {};
  f32x4 aR[2] = {};
#pragma unroll
  for (int mf = 0; mf < 2; ++mf) {
#pragma unroll
    for (int nf = 0; nf < 2; ++nf)
      aK[mf][nf] =
          __builtin_amdgcn_mfma_f32_16x16x32_bf16(qf[mf], kef[nf], aK[mf][nf], 0, 0, 0);
    aR[mf] = __builtin_amdgcn_mfma_f32_16x16x32_bf16(qf[mf], rf, aR[mf], 0, 0, 0);
  }

  // dump QR to LDS: QR[v][hp], stride 18 (2-way max bank aliasing)
#pragma unroll
  for (int mf = 0; mf < 2; ++mf)
#pragma unroll
    for (int r = 0; r < 4; ++r)
      QRp[(mf * 16 + g * 4 + r) * 18 + lm] = aR[mf][r];

  // ---- epilogue: bias-gather + softmax (register butterfly) + P write ----
  const bool w1ok = (lm + 16) < kV;
#pragma unroll
  for (int mf = 0; mf < 2; ++mf) {
#pragma unroll
    for (int r = 0; r < 4; ++r) {
      int v = mf * 16 + g * 4 + r;
      int vc = v < kV ? v : kV - 1;
      int hp0 = hopsS[vc][lm];
      int hp1 = hopsS[vc][lm + 16];
      float s0 = (aK[mf][0][r] + QRp[v * 18 + hp0] + dt[0]) * kScale;
      float s1 = (aK[mf][1][r] + QRp[v * 18 + hp1] + dt[1]) * kScale;
      if (!w1ok) s1 = -3.0e38f;
      float m = fmaxf(s0, s1);
#pragma unroll
      for (int d = 1; d < 16; d <<= 1) m = fmaxf(m, __shfl_xor(m, d));
      float e0 = __expf(s0 - m);
      float e1 = w1ok ? __expf(s1 - m) : 0.f;
      float sum = e0 + e1;
#pragma unroll
      for (int d = 1; d < 16; d <<= 1) sum += __shfl_xor(sum, d);
      float inv = alpha / sum;
      float o0 = outer[h * (kV * kV) + vc * kV + lm];
      float o1 = w1ok ? outer[h * (kV * kV) + vc * kV + lm + 16] : 0.f;
      Pp[v * 40 + lm] = __float2bfloat16(e0 * inv + o0);
      Pp[v * 40 + lm + 16] = __float2bfloat16(w1ok ? e1 * inv + o1 : 0.f);
    }
  }

  // ---- PV: O[v][d] = P @ V, V fragments straight from global VT ----
  bf16x8 pa[2], vb[2];
#pragma unroll
  for (int mf = 0; mf < 2; ++mf)
    pa[mf] = *reinterpret_cast<const bf16x8*>(Pp + (mf * 16 + lm) * 40 + g * 8);
#pragma unroll
  for (int nf = 0; nf < 2; ++nf)
    vb[nf] = *reinterpret_cast<const bf16x8*>(
        VT + ((size_t)(nt * kDim + h * kHd + nf * 16 + lm)) * 32 + g * 8);
  f32x4 aO[2][2] = {};
#pragma unroll
  for (int mf = 0; mf < 2; ++mf)
#pragma unroll
    for (int nf = 0; nf < 2; ++nf)
      aO[mf][nf] =
          __builtin_amdgcn_mfma_f32_16x16x32_bf16(pa[mf], vb[nf], aO[mf][nf], 0, 0, 0);

  // ---- O -> LDS (bf16), then grouped proj via MFMA (swapped operands:
  //      oo on regs, v on lanes -> coalesced residual load/store) ----
#pragma unroll
  for (int mf = 0; mf < 2; ++mf)
#pragma unroll
    for (int nf = 0; nf < 2; ++nf)
#pragma unroll
      for (int r = 0; r < 4; ++r)
        OLp[(mf * 16 + g * 4 + r) * 40 + nf * 16 + lm] =
            __float2bfloat16(aO[mf][nf][r]);

  bf16x8 oa[2], pwf[2];
#pragma unroll
  for (int nf = 0; nf < 2; ++nf)
    oa[nf] = *reinterpret_cast<const bf16x8*>(OLp + (nf * 16 + lm) * 40 + g * 8);
#pragma unroll
  for (int mf = 0; mf < 2; ++mf)
    pwf[mf] = *reinterpret_cast<const bf16x8*>(pwb +
        (h * kHd + mf * 16 + lm) * kHd + g * 8);
  f32x4 aF[2][2] = {};
#pragma unroll
  for (int mf = 0; mf < 2; ++mf)
#pragma unroll
    for (int nf = 0; nf < 2; ++nf)
      aF[mf][nf] =
          __builtin_amdgcn_mfma_f32_16x16x32_bf16(pwf[mf], oa[nf], aF[mf][nf], 0, 0, 0);

  // ---- bias + residual store into [n][c][t][v]: v on lanes = coalesced ----
#pragma unroll
  for (int mf = 0; mf < 2; ++mf) {
#pragma unroll
    for (int r = 0; r < 4; ++r) {
      int oo = mf * 16 + g * 4 + r;
      int c = h * kHd + oo;
      float pbv = proj_b[c];
      size_t gbase = (size_t)n * kNCstride + (size_t)c * kP + t * kV;
#pragma unroll
      for (int nf = 0; nf < 2; ++nf) {
        int v = nf * 16 + lm;
        if (v < kV) out[gbase + v] = x[gbase + v] + aF[mf][nf][r] + pbv;
      }
    }
  }
}

extern "C" void kernel_launch(void* const* d_in, const int* in_sizes, int n_in,
                              void* d_out, int out_size, void* d_ws,
                              size_t ws_size, hipStream_t stream) {
  const float* x = (const float*)d_in[0];
  const int* joint_label = (const int*)d_in[1];
  const float* he_weight = (const float*)d_in[3];
  const int* hops = (const int*)d_in[4];
  const float* ln_g = (const float*)d_in[5];
  const float* ln_b = (const float*)d_in[6];
  const float* hgc_w = (const float*)d_in[7];
  const float* q_w = (const float*)d_in[8];
  const float* kv_w = (const float*)d_in[9];
  const float* proj_w = (const float*)d_in[10];
  const float* proj_b = (const float*)d_in[11];
  const float* rpe = (const float*)d_in[12];
  const float* w1 = (const float*)d_in[13];
  const float* outer = (const float*)d_in[14];
  const float* alpha = (const float*)d_in[15];
  const float* lin1_w = (const float*)d_in[16];
  const float* lin1_b = (const float*)d_in[17];
  const float* lin2_w = (const float*)d_in[18];
  const float* lin2_b = (const float*)d_in[19];
  const int n_hop = in_sizes[12] / kDim;

  // workspace layout (QK region hosts XB, which dies before gemm2 writes QK)
  char* w = (char*)d_ws;
  bf16* QK = (bf16*)w;                        // [n][p][384], 78.6 MB
  bf16* XB = (bf16*)w;                        // [n][p][192], first 39.3 MB
  w += (size_t)kN * kP * 2 * kDim * 2;
  bf16* XL = (bf16*)w;                        // [n][p][192]
  w += (size_t)kN * kP * kDim * 2;
  bf16* OP = (bf16*)w;                        // [n][p][192]
  w += (size_t)kN * kP * kDim * 2;
  w += 65536;                                 // slack for padded-row overreads
  bf16* VT = (bf16*)w;                        // [n*t][192][32], 50.3 MB
  w += (size_t)kN * kT * kDim * 32 * 2;
  bf16* Wb = (bf16*)w;                        // 768x192 bf16
  w += (size_t)768 * kDim * 2;
  bf16* RPEb = (bf16*)w;                      // [6][16][32] bf16
  w += (size_t)kH * 16 * kHd * 2;
  bf16* pwb = (bf16*)w;                       // [192][32] bf16
  w += (size_t)kDim * kHd * 2;
  float* hadj = (float*)w;
  w += 1024 * 4;
  float* s_ws = (float*)w;
  w += kN * kT * 4;
  float* gatef = (float*)w;
  w += kN * kT * 4;

  hipLaunchKernelGGL(setup_kernel, dim3(3650), dim3(256), 0, stream,
                     joint_label, he_weight, hgc_w, q_w, kv_w, rpe, proj_w,
                     n_hop, hadj, Wb, RPEb, pwb, VT);
  hipLaunchKernelGGL(prep_kernel, dim3(kT, kN), dim3(256), 0, stream, x, hadj,
                     ln_g, ln_b, XB, XL);
  // OP[n][p][o] = hgc_w @ z  (before gemm2 overwrites aliased XB)
  hipLaunchKernelGGL((mfma_gemm_kernel<3, kDim, false>), dim3(25 * 3 * kN),
                     dim3(64), 0, stream, Wb, XB, OP, nullptr);
  hipLaunchKernelGGL(sred_kernel, dim3(kN * kT), dim3(64), 0, stream, OP, s_ws);
  hipLaunchKernelGGL(gate_kernel, dim3(kN), dim3(kT), 0, stream, s_ws, lin1_w,
                     lin1_b, lin2_w, lin2_b, gatef);
  // QK[n][p][0:384] = [q_w; k_w] @ LN(x); V third -> VT transposed
  hipLaunchKernelGGL((mfma_gemm_kernel<9, 384, true>), dim3(25 * 9 * kN),
                     dim3(64), 0, stream, Wb + 192 * kDim, XL, QK, VT);
  hipLaunchKernelGGL(attn_kernel, dim3(kT, kN), dim3(384), 0, stream, QK, VT,
                     OP, gatef, hops, RPEb, w1, outer, alpha, pwb, proj_b, x,
                     (float*)d_out);
}

// Round 5
// 354.620 us; speedup vs baseline: 4.2568x; 1.2276x over previous
//
#include <hip/hip_runtime.h>
#include <hip/hip_bf16.h>

using bf16 = __hip_bfloat16;
typedef __bf16 bf16x8 __attribute__((ext_vector_type(8)));
typedef float f32x4 __attribute__((ext_vector_type(4)));

constexpr int kDim = 192;
constexpr int kH = 6;
constexpr int kHd = 32;
constexpr int kN = 64;
constexpr int kT = 64;
constexpr int kV = 25;
constexpr int kP = kT * kV;            // 1600 positions per n
constexpr int kNCstride = kDim * kP;   // 307200, per-n stride of (c,t,v)
constexpr float kScale = 0.17677669529663687f;  // 32^-0.5
constexpr float kCoeff = 0.4f;

// ---- setup: h_adj, weights->bf16 (g folded), G/Bb, rpe/proj pack, VT pad ---
__global__ void __launch_bounds__(256) setup_kernel(
    const int* __restrict__ jl, const float* __restrict__ hew,
    const float* __restrict__ hgc, const float* __restrict__ qw,
    const float* __restrict__ kvw, const float* __restrict__ rpe,
    const float* __restrict__ proj_w, const float* __restrict__ lng,
    const float* __restrict__ lnb, int n_hop, float* __restrict__ hadj,
    bf16* __restrict__ Wb, float* __restrict__ G, float* __restrict__ Bb,
    bf16* __restrict__ RPEb, bf16* __restrict__ pwb, bf16* __restrict__ VT) {
  const int bid = blockIdx.x;
  const int tid = threadIdx.x;
  if (bid < 576) {  // Wb[768][192]: rows 0..191 hgc raw; 192..767 [q;kv]*g
    int i = bid * 256 + tid;
    float v;
    if (i < 36864) {
      v = hgc[i];
    } else {
      int local = i - 36864;
      int c = local % kDim;
      v = (local < 36864) ? qw[local] : kvw[local - 36864];
      v *= lng[c];
    }
    Wb[i] = __float2bfloat16(v);
  } else if (bid == 576) {  // h_adj from labels
    __shared__ int lbl[kV];
    __shared__ int cnt[8];
    if (tid < 8) cnt[tid] = 0;
    __syncthreads();
    if (tid < kV) { lbl[tid] = jl[tid]; atomicAdd(&cnt[lbl[tid]], 1); }
    __syncthreads();
    for (int idx = tid; idx < kV * kV; idx += 256) {
      int v = idx / kV, w = idx - v * kV;
      float val = 0.f;
      if (lbl[v] == lbl[w]) val = hew[lbl[v]] / (float)cnt[lbl[v]];
      hadj[idx] = val;
    }
  } else if (bid == 577) {  // pack rpe (zero-padded to 16 hops) + proj_w
    for (int i = tid; i < kH * 16 * kHd; i += 256) {
      int h = i >> 9, hp = (i >> 5) & 15, d = i & 31;
      float v = (hp < n_hop) ? rpe[hp * kDim + h * kHd + d] : 0.f;
      RPEb[i] = __float2bfloat16(v);
    }
    for (int i = tid; i < kDim * kHd; i += 256)
      pwb[i] = __float2bfloat16(proj_w[i]);
  } else if (bid < 722) {  // G[o] = sum W[o][c]*g[c]; Bb[o] = sum W[o][c]*b[c]
    int o = (bid - 578) * 4 + (tid >> 6);
    int lane = tid & 63;
    const float* Wr =
        (o < kDim) ? (qw + (size_t)o * kDim) : (kvw + (size_t)(o - kDim) * kDim);
    float gs = 0.f, bs = 0.f;
    for (int c = lane; c < kDim; c += 64) {
      float wv = Wr[c];
      gs += wv * lng[c];
      bs += wv * lnb[c];
    }
    for (int off = 32; off > 0; off >>= 1) {
      gs += __shfl_down(gs, off);
      bs += __shfl_down(bs, off);
    }
    if (lane == 0) { G[o] = gs; Bb[o] = bs; }
  } else {  // zero VT pad cols 24..31 (one 16B store per row)
    int row = (bid - 722) * 256 + tid;
    if (row < kN * kT * kDim) {
      uint4 z = {0u, 0u, 0u, 0u};
      *reinterpret_cast<uint4*>(reinterpret_cast<char*>(VT) + (size_t)row * 64 +
                                48) = z;
    }
  }
}

// ------- prep per (n,t): pure transpose f32->bf16 + LN stats, no data LDS ---
__global__ void __launch_bounds__(256) prep_kernel(
    const float* __restrict__ x, bf16* __restrict__ XR, float* __restrict__ mu,
    float* __restrict__ rstd) {
  __shared__ float ps[kV][25], ps2[kV][25];
  const int tid = threadIdx.x;
  const int t = blockIdx.x, n = blockIdx.y;
  const float* xb = x + (size_t)n * kNCstride + t * kV;
  size_t ob = ((size_t)n * kP + t * kV) * kDim;
  for (int idx = tid; idx < 600; idx += 256) {
    int p = idx % 25, c8 = idx / 25;  // p fastest -> coalesced row reads
    float a = 0.f, b = 0.f;
    union { uint4 u; __bf16 h[8]; } pk;
#pragma unroll
    for (int i = 0; i < 8; ++i) {
      float v = xb[(size_t)(c8 * 8 + i) * kP + p];
      a += v;
      b += v * v;
      pk.h[i] = (__bf16)v;
    }
    *reinterpret_cast<uint4*>(XR + ob + (size_t)p * kDim + c8 * 8) = pk.u;
    ps[p][c8] = a;
    ps2[p][c8] = b;
  }
  __syncthreads();
  if (tid < kV) {
    float a = 0.f, b = 0.f;
#pragma unroll
    for (int c8 = 0; c8 < 24; ++c8) { a += ps[tid][c8]; b += ps2[tid][c8]; }
    float m = a * (1.f / kDim);
    float var = b * (1.f / kDim) - m * m;
    int gid = n * kP + t * kV + tid;
    mu[gid] = m;
    rstd[gid] = rsqrtf(var + 1e-5f);
  }
}

// ---- MFMA GEMM: out[n][p][o] = A[o][k]*B[n][p][k]; optional LN-fix epilogue,
//      optional V-third -> VT transposed. B-tile-sharing blocks contiguous. --
template <int OBN, int MOUT, bool VS, bool LNF>
__global__ void __launch_bounds__(64) mfma_gemm_kernel(
    const bf16* __restrict__ A, const bf16* __restrict__ B,
    bf16* __restrict__ out, bf16* __restrict__ VT,
    const float* __restrict__ muA, const float* __restrict__ rsA,
    const float* __restrict__ G, const float* __restrict__ Bb) {
  int id = blockIdx.x;
  int per = gridDim.x >> 3;  // grid % 8 == 0
  int wg = (id & 7) * per + (id >> 3);
  int n = wg / (25 * OBN);
  int rem = wg - n * (25 * OBN);
  const int pb = (rem / OBN) * 64;
  const int ob = (rem % OBN) * 64;
  const int l = threadIdx.x;
  B += (size_t)n * kNCstride;
  out += (size_t)n * kP * MOUT;
  f32x4 acc[4][4] = {};
  const int lm = l & 15;
  const int lk = (l >> 4) * 8;
  for (int kb = 0; kb < kDim; kb += 32) {
    bf16x8 af[4], bfv[4];
#pragma unroll
    for (int mf = 0; mf < 4; ++mf)
      af[mf] = *reinterpret_cast<const bf16x8*>(
          A + (size_t)(ob + mf * 16 + lm) * kDim + kb + lk);
#pragma unroll
    for (int nf = 0; nf < 4; ++nf)
      bfv[nf] = *reinterpret_cast<const bf16x8*>(
          B + (size_t)(pb + nf * 16 + lm) * kDim + kb + lk);
#pragma unroll
    for (int mf = 0; mf < 4; ++mf)
#pragma unroll
      for (int nf = 0; nf < 4; ++nf)
        acc[mf][nf] = __builtin_amdgcn_mfma_f32_16x16x32_bf16(
            af[mf], bfv[nf], acc[mf][nf], 0, 0, 0);
  }
  const int r0 = (l >> 4) * 4;
  float rsv[4], muv[4];
  if (LNF) {
#pragma unroll
    for (int nf = 0; nf < 4; ++nf) {
      int p = pb + nf * 16 + lm;
      rsv[nf] = rsA[n * kP + p];
      muv[nf] = muA[n * kP + p];
    }
  }
  int tt[4], vv[4];
#pragma unroll
  for (int nf = 0; nf < 4; ++nf) {
    int p = pb + nf * 16 + lm;
    tt[nf] = p / 25;
    vv[nf] = p - tt[nf] * 25;
  }
#pragma unroll
  for (int mf = 0; mf < 4; ++mf) {
    const int o0 = ob + mf * 16 + r0;
    float ga[4] = {0.f, 0.f, 0.f, 0.f}, ba[4] = {0.f, 0.f, 0.f, 0.f};
    if (LNF) {
      float4 g4 = *reinterpret_cast<const float4*>(G + o0);
      float4 b4 = *reinterpret_cast<const float4*>(Bb + o0);
      ga[0] = g4.x; ga[1] = g4.y; ga[2] = g4.z; ga[3] = g4.w;
      ba[0] = b4.x; ba[1] = b4.y; ba[2] = b4.z; ba[3] = b4.w;
    }
    if (!VS || o0 < 384) {
#pragma unroll
      for (int nf = 0; nf < 4; ++nf) {
        const int p = pb + nf * 16 + lm;
        union { uint2 u; bf16 b[4]; } pk;
#pragma unroll
        for (int r = 0; r < 4; ++r) {
          float vvv = acc[mf][nf][r];
          if (LNF) vvv = rsv[nf] * (vvv - muv[nf] * ga[r]) + ba[r];
          pk.b[r] = __float2bfloat16(vvv);
        }
        *reinterpret_cast<uint2*>(out + (size_t)p * MOUT + o0) = pk.u;
      }
    } else {  // V third: write transposed VT[(n*64+t)*192 + d][v]
#pragma unroll
      for (int nf = 0; nf < 4; ++nf) {
        size_t rowb =
            ((size_t)(n * kT + tt[nf]) * kDim + (o0 - 384)) * 32 + vv[nf];
#pragma unroll
        for (int r = 0; r < 4; ++r) {
          float vvv = acc[mf][nf][r];
          if (LNF) vvv = rsv[nf] * (vvv - muv[nf] * ga[r]) + ba[r];
          VT[rowb + (size_t)r * 32] = __float2bfloat16(vvv);
        }
      }
    }
  }
}

// ------ h_adj apply on OP (in place, [p][c] layout) + fused sred sum -------
__global__ void __launch_bounds__(256) haapply_kernel(
    bf16* __restrict__ OP, const float* __restrict__ hadjg,
    float* __restrict__ s_out) {
  __shared__ ushort tile[kV * kDim];  // 9.6 KB
  __shared__ float ha[640];
  __shared__ float red[4];
  const int tid = threadIdx.x;
  const int t = blockIdx.x, n = blockIdx.y;
  size_t base = ((size_t)n * kP + t * kV) * kDim;
  for (int i = tid; i < kV * kV; i += 256) ha[i] = hadjg[i];
  const uint2* src = reinterpret_cast<const uint2*>(OP + base);
  uint2* dst2 = reinterpret_cast<uint2*>(tile);
  for (int i = tid; i < kV * kDim / 4; i += 256) dst2[i] = src[i];
  __syncthreads();
  float ssum = 0.f;
  for (int idx = tid; idx < 600; idx += 256) {
    int c8 = idx % 24, w = idx / 24;  // c8 fastest -> coalesced writes
    float acc[8] = {0.f, 0.f, 0.f, 0.f, 0.f, 0.f, 0.f, 0.f};
    for (int v = 0; v < kV; ++v) {
      float coef = ha[v * kV + w];
      union { uint4 u; __bf16 h[8]; } ld;
      ld.u = *reinterpret_cast<const uint4*>(tile + v * kDim + c8 * 8);
#pragma unroll
      for (int j = 0; j < 8; ++j) acc[j] += coef * (float)ld.h[j];
    }
    union { uint4 u; __bf16 h[8]; } pk;
    float s8 = 0.f;
#pragma unroll
    for (int j = 0; j < 8; ++j) { pk.h[j] = (__bf16)acc[j]; s8 += acc[j]; }
    *reinterpret_cast<uint4*>(OP + base + (size_t)w * kDim + c8 * 8) = pk.u;
    ssum += s8;
  }
  for (int off = 32; off > 0; off >>= 1) ssum += __shfl_down(ssum, off);
  if ((tid & 63) == 0) red[tid >> 6] = ssum;
  __syncthreads();
  if (tid == 0)
    s_out[n * kT + t] = (red[0] + red[1] + red[2] + red[3]) *
                        (1.f / (float)(kDim * kV));
}

// ---------------- SE gate MLP -> factor f[n,t] = 1 + 0.4*sigmoid(...) -------
__global__ void gate_kernel(const float* __restrict__ s,
                            const float* __restrict__ w1l,
                            const float* __restrict__ b1,
                            const float* __restrict__ w2l,
                            const float* __restrict__ b2,
                            float* __restrict__ gatef) {
  __shared__ float sh[kT];
  __shared__ float hid[12];
  int n = blockIdx.x, t = threadIdx.x;
  sh[t] = s[n * kT + t];
  __syncthreads();
  if (t < 12) {
    float a = b1[t];
    for (int j = 0; j < kT; ++j) a += sh[j] * w1l[t * kT + j];
    hid[t] = fmaxf(a, 0.f);
  }
  __syncthreads();
  float a = b2[t];
  for (int j = 0; j < 12; ++j) a += hid[j] * w2l[t * 12 + j];
  float g = 1.f / (1.f + __expf(-a));
  gatef[n * kT + t] = 1.f + kCoeff * g;
}

// ---------- MFMA attention: block = (n,t), 6 waves, wave = head ------------
__global__ void __launch_bounds__(384) attn_kernel(
    const bf16* __restrict__ QK, const bf16* __restrict__ VT,
    const bf16* __restrict__ OP, const float* __restrict__ gatef,
    const int* __restrict__ hops, const bf16* __restrict__ RPEb,
    const float* __restrict__ w1, const float* __restrict__ outer,
    const float* __restrict__ alpha_p, const bf16* __restrict__ pwb,
    const float* __restrict__ proj_b, const float* __restrict__ x,
    float* __restrict__ out) {
  // per-wave LDS: P[32][40] bf16 | (QR[32][18] f32 alias OL[32][40] bf16)
  __shared__ ushort wls[kH][2560];
  __shared__ int hopsS[kV][32];
  const int tid = threadIdx.x;
  const int lane = tid & 63;
  const int h = tid >> 6;  // wave id = head
  const int t = blockIdx.x, n = blockIdx.y;
  const int nt = n * kT + t;
  const int lm = lane & 15, g = lane >> 4;

  for (int i = tid; i < kV * 32; i += 384) {
    int v = i >> 5, w = i & 31;
    hopsS[v][w] = (w < kV) ? hops[v * kV + w] : 0;
  }
  __syncthreads();

  bf16* Pp = (bf16*)&wls[h][0];       // [32][40]
  bf16* OLp = (bf16*)&wls[h][1280];   // [32][40]
  float* QRp = (float*)&wls[h][1280]; // [32][18] (alias, used before OLp)

  const float f = gatef[nt];
  const float alpha = alpha_p[0];
  const bf16* Qbase = QK + (size_t)(n * kP + t * kV) * 384;
  const bf16* Ebase = OP + (size_t)(n * kP + t * kV) * kDim;
  const int colO = h * kHd + g * 8;

  // ---- fragment loads (direct from global, k-contiguous 16B) ----
  bf16x8 qf[2], kf[2], ef[2];
#pragma unroll
  for (int mf = 0; mf < 2; ++mf) {
    const bf16* row = Qbase + (size_t)(mf * 16 + lm) * 384;
    qf[mf] = *reinterpret_cast<const bf16x8*>(row + colO);
    kf[mf] = *reinterpret_cast<const bf16x8*>(row + kDim + colO);
    ef[mf] = *reinterpret_cast<const bf16x8*>(
        Ebase + (size_t)(mf * 16 + lm) * kDim + colO);
  }
  bf16x8 rf = *reinterpret_cast<const bf16x8*>(RPEb + (h * 16 + lm) * kHd + g * 8);

  // ---- d-term from raw E frags: dt[nf] = f * sum_d w1[h,d]*e[w,d] ----
  float w1v[8];
  {
    float4 wa = *reinterpret_cast<const float4*>(w1 + h * kHd + g * 8);
    float4 wb = *reinterpret_cast<const float4*>(w1 + h * kHd + g * 8 + 4);
    w1v[0] = wa.x; w1v[1] = wa.y; w1v[2] = wa.z; w1v[3] = wa.w;
    w1v[4] = wb.x; w1v[5] = wb.y; w1v[6] = wb.z; w1v[7] = wb.w;
  }
  float dt[2];
#pragma unroll
  for (int nf = 0; nf < 2; ++nf) {
    float a = 0.f;
#pragma unroll
    for (int j = 0; j < 8; ++j) a += w1v[j] * (float)ef[nf][j];
    a += __shfl_xor(a, 16);
    a += __shfl_xor(a, 32);
    dt[nf] = f * a;
  }

  // ---- fold gate into K: ke = k + f*e (bf16) ----
  bf16x8 kef[2];
#pragma unroll
  for (int nf = 0; nf < 2; ++nf)
#pragma unroll
    for (int j = 0; j < 8; ++j)
      kef[nf][j] = (__bf16)((float)kf[nf][j] + f * (float)ef[nf][j]);

  // ---- S = Q(KE)^T and QR = Q rpe^T via MFMA ----
  f32x4 aK[2][2] = {};
  f32x4 aR[2] = {};
#pragma unroll
  for (int mf = 0; mf < 2; ++mf) {
#pragma unroll
    for (int nf = 0; nf < 2; ++nf)
      aK[mf][nf] =
          __builtin_amdgcn_mfma_f32_16x16x32_bf16(qf[mf], kef[nf], aK[mf][nf], 0, 0, 0);
    aR[mf] = __builtin_amdgcn_mfma_f32_16x16x32_bf16(qf[mf], rf, aR[mf], 0, 0, 0);
  }

  // dump QR to LDS: QR[v][hp], stride 18 (2-way max bank aliasing)
#pragma unroll
  for (int mf = 0; mf < 2; ++mf)
#pragma unroll
    for (int r = 0; r < 4; ++r)
      QRp[(mf * 16 + g * 4 + r) * 18 + lm] = aR[mf][r];

  // ---- epilogue: bias-gather + softmax (register butterfly) + P write ----
  const bool w1ok = (lm + 16) < kV;
#pragma unroll
  for (int mf = 0; mf < 2; ++mf) {
#pragma unroll
    for (int r = 0; r < 4; ++r) {
      int v = mf * 16 + g * 4 + r;
      int vc = v < kV ? v : kV - 1;
      int hp0 = hopsS[vc][lm];
      int hp1 = hopsS[vc][lm + 16];
      float s0 = (aK[mf][0][r] + QRp[v * 18 + hp0] + dt[0]) * kScale;
      float s1 = (aK[mf][1][r] + QRp[v * 18 + hp1] + dt[1]) * kScale;
      if (!w1ok) s1 = -3.0e38f;
      float m = fmaxf(s0, s1);
#pragma unroll
      for (int d = 1; d < 16; d <<= 1) m = fmaxf(m, __shfl_xor(m, d));
      float e0 = __expf(s0 - m);
      float e1 = w1ok ? __expf(s1 - m) : 0.f;
      float sum = e0 + e1;
#pragma unroll
      for (int d = 1; d < 16; d <<= 1) sum += __shfl_xor(sum, d);
      float inv = alpha / sum;
      float o0 = outer[h * (kV * kV) + vc * kV + lm];
      float o1 = w1ok ? outer[h * (kV * kV) + vc * kV + lm + 16] : 0.f;
      Pp[v * 40 + lm] = __float2bfloat16(e0 * inv + o0);
      Pp[v * 40 + lm + 16] = __float2bfloat16(w1ok ? e1 * inv + o1 : 0.f);
    }
  }

  // ---- PV: O[v][d] = P @ V, V fragments straight from global VT ----
  bf16x8 pa[2], vb[2];
#pragma unroll
  for (int mf = 0; mf < 2; ++mf)
    pa[mf] = *reinterpret_cast<const bf16x8*>(Pp + (mf * 16 + lm) * 40 + g * 8);
#pragma unroll
  for (int nf = 0; nf < 2; ++nf)
    vb[nf] = *reinterpret_cast<const bf16x8*>(
        VT + ((size_t)(nt * kDim + h * kHd + nf * 16 + lm)) * 32 + g * 8);
  f32x4 aO[2][2] = {};
#pragma unroll
  for (int mf = 0; mf < 2; ++mf)
#pragma unroll
    for (int nf = 0; nf < 2; ++nf)
      aO[mf][nf] =
          __builtin_amdgcn_mfma_f32_16x16x32_bf16(pa[mf], vb[nf], aO[mf][nf], 0, 0, 0);

  // ---- O -> LDS (bf16), then grouped proj via MFMA (swapped operands:
  //      oo on regs, v on lanes -> coalesced residual load/store) ----
#pragma unroll
  for (int mf = 0; mf < 2; ++mf)
#pragma unroll
    for (int nf = 0; nf < 2; ++nf)
#pragma unroll
      for (int r = 0; r < 4; ++r)
        OLp[(mf * 16 + g * 4 + r) * 40 + nf * 16 + lm] =
            __float2bfloat16(aO[mf][nf][r]);

  bf16x8 oa[2], pwf[2];
#pragma unroll
  for (int nf = 0; nf < 2; ++nf)
    oa[nf] = *reinterpret_cast<const bf16x8*>(OLp + (nf * 16 + lm) * 40 + g * 8);
#pragma unroll
  for (int mf = 0; mf < 2; ++mf)
    pwf[mf] = *reinterpret_cast<const bf16x8*>(pwb +
        (h * kHd + mf * 16 + lm) * kHd + g * 8);
  f32x4 aF[2][2] = {};
#pragma unroll
  for (int mf = 0; mf < 2; ++mf)
#pragma unroll
    for (int nf = 0; nf < 2; ++nf)
      aF[mf][nf] =
          __builtin_amdgcn_mfma_f32_16x16x32_bf16(pwf[mf], oa[nf], aF[mf][nf], 0, 0, 0);

  // ---- bias + residual store into [n][c][t][v]: v on lanes = coalesced ----
#pragma unroll
  for (int mf = 0; mf < 2; ++mf) {
#pragma unroll
    for (int r = 0; r < 4; ++r) {
      int oo = mf * 16 + g * 4 + r;
      int c = h * kHd + oo;
      float pbv = proj_b[c];
      size_t gbase = (size_t)n * kNCstride + (size_t)c * kP + t * kV;
#pragma unroll
      for (int nf = 0; nf < 2; ++nf) {
        int v = nf * 16 + lm;
        if (v < kV) out[gbase + v] = x[gbase + v] + aF[mf][nf][r] + pbv;
      }
    }
  }
}

extern "C" void kernel_launch(void* const* d_in, const int* in_sizes, int n_in,
                              void* d_out, int out_size, void* d_ws,
                              size_t ws_size, hipStream_t stream) {
  const float* x = (const float*)d_in[0];
  const int* joint_label = (const int*)d_in[1];
  const float* he_weight = (const float*)d_in[3];
  const int* hops = (const int*)d_in[4];
  const float* ln_g = (const float*)d_in[5];
  const float* ln_b = (const float*)d_in[6];
  const float* hgc_w = (const float*)d_in[7];
  const float* q_w = (const float*)d_in[8];
  const float* kv_w = (const float*)d_in[9];
  const float* proj_w = (const float*)d_in[10];
  const float* proj_b = (const float*)d_in[11];
  const float* rpe = (const float*)d_in[12];
  const float* w1 = (const float*)d_in[13];
  const float* outer = (const float*)d_in[14];
  const float* alpha = (const float*)d_in[15];
  const float* lin1_w = (const float*)d_in[16];
  const float* lin1_b = (const float*)d_in[17];
  const float* lin2_w = (const float*)d_in[18];
  const float* lin2_b = (const float*)d_in[19];
  const int n_hop = in_sizes[12] / kDim;

  char* w = (char*)d_ws;
  bf16* QK = (bf16*)w;                        // [n][p][384], 78.6 MB
  w += (size_t)kN * kP * 2 * kDim * 2;
  bf16* XR = (bf16*)w;                        // [n][p][192] bf16(x), 39.3 MB
  w += (size_t)kN * kP * kDim * 2;
  bf16* OP = (bf16*)w;                        // [n][p][192]
  w += (size_t)kN * kP * kDim * 2;
  w += 65536;                                 // slack for padded-row overreads
  bf16* VT = (bf16*)w;                        // [n*t][192][32], 50.3 MB
  w += (size_t)kN * kT * kDim * 32 * 2;
  bf16* Wb = (bf16*)w;                        // 768x192 bf16
  w += (size_t)768 * kDim * 2;
  bf16* RPEb = (bf16*)w;                      // [6][16][32] bf16
  w += (size_t)kH * 16 * kHd * 2;
  bf16* pwb = (bf16*)w;                       // [192][32] bf16
  w += (size_t)kDim * kHd * 2;
  float* hadj = (float*)w;
  w += 1024 * 4;
  float* s_ws = (float*)w;
  w += kN * kT * 4;
  float* gatef = (float*)w;
  w += kN * kT * 4;
  float* mu = (float*)w;
  w += (size_t)kN * kP * 4;
  float* rstd = (float*)w;
  w += (size_t)kN * kP * 4;
  float* G = (float*)w;
  w += 576 * 4;
  float* Bb = (float*)w;
  w += 576 * 4;

  hipLaunchKernelGGL(setup_kernel, dim3(3794), dim3(256), 0, stream,
                     joint_label, he_weight, hgc_w, q_w, kv_w, rpe, proj_w,
                     ln_g, ln_b, n_hop, hadj, Wb, G, Bb, RPEb, pwb, VT);
  hipLaunchKernelGGL(prep_kernel, dim3(kT, kN), dim3(256), 0, stream, x, XR,
                     mu, rstd);
  // OP = hgc_w @ x (raw); h_adj applied afterwards (commutes)
  hipLaunchKernelGGL((mfma_gemm_kernel<3, kDim, false, false>),
                     dim3(25 * 3 * kN), dim3(64), 0, stream, Wb, XR, OP,
                     (bf16*)nullptr, nullptr, nullptr, nullptr, nullptr);
  hipLaunchKernelGGL(haapply_kernel, dim3(kT, kN), dim3(256), 0, stream, OP,
                     hadj, s_ws);
  hipLaunchKernelGGL(gate_kernel, dim3(kN), dim3(kT), 0, stream, s_ws, lin1_w,
                     lin1_b, lin2_w, lin2_b, gatef);
  // QK/V = (Wg @ x) with LN folded via rstd/mu/G/Bb epilogue
  hipLaunchKernelGGL((mfma_gemm_kernel<9, 384, true, true>),
                     dim3(25 * 9 * kN), dim3(64), 0, stream, Wb + 192 * kDim,
                     XR, QK, VT, mu, rstd, G, Bb);
  hipLaunchKernelGGL(attn_kernel, dim3(kT, kN), dim3(384), 0, stream, QK, VT,
                     OP, gatef, hops, RPEb, w1, outer, alpha, pwb, proj_b, x,
                     (float*)d_out);
}